// Round 1
// baseline (103050.635 us; speedup 1.0000x reference)
//
#include <hip/hip_runtime.h>
#include <math.h>

#define B_      16
#define SEQ_    513
#define D_      768
#define NH_     12
#define DH_     64
#define L_      12
#define FF_     3072
#define NPATCH_ 512
#define NSP_    128
#define NST_    385            // NPATCH - NSP + 1
#define TOK_    (B_ * SEQ_)    // 8208
#define EPS_    1e-5f

// ---------------------------------------------------------------------------
// Generic fp32 tiled GEMM: C[M,N] = act(A[M,K] @ B[K,N] + bias) (+= if beta)
// BM=BN=64, BK=16, 256 threads, 4x4 per-thread microtile.
// Requires N%64==0, K%16==0 (true for all call sites); M guarded.
// ---------------------------------------------------------------------------
#define BM 64
#define BN 64
#define BK 16

__global__ __launch_bounds__(256) void gemm_f32(
    const float* __restrict__ A, const float* __restrict__ Bm,
    const float* __restrict__ bias, float* __restrict__ C,
    int M, int N, int K, int act, int beta)
{
    __shared__ float As[BK][BM];
    __shared__ float Bs[BK][BN];
    const int tid  = threadIdx.x;
    const int row0 = blockIdx.y * BM;
    const int col0 = blockIdx.x * BN;
    const int ty4  = (tid >> 4) * 4;   // 0..60
    const int tx4  = (tid & 15) * 4;   // 0..60

    // load indices: A tile 64x16, B tile 16x64, 4 floats per thread each
    const int la   = tid * 4;
    const int arow = la >> 4;          // 0..63
    const int ak   = la & 15;          // 0,4,8,12
    const int brow = la >> 6;          // 0..15
    const int bcol = la & 63;

    float acc[4][4] = {};

    for (int k0 = 0; k0 < K; k0 += BK) {
        float4 av;
        if (row0 + arow < M)
            av = *(const float4*)(A + (size_t)(row0 + arow) * K + k0 + ak);
        else
            av = make_float4(0.f, 0.f, 0.f, 0.f);
        As[ak + 0][arow] = av.x;
        As[ak + 1][arow] = av.y;
        As[ak + 2][arow] = av.z;
        As[ak + 3][arow] = av.w;

        float4 bv = *(const float4*)(Bm + (size_t)(k0 + brow) * N + col0 + bcol);
        *(float4*)&Bs[brow][bcol] = bv;

        __syncthreads();
#pragma unroll
        for (int k = 0; k < BK; ++k) {
            const float4 a = *(const float4*)&As[k][ty4];
            const float4 b = *(const float4*)&Bs[k][tx4];
            acc[0][0] += a.x * b.x; acc[0][1] += a.x * b.y; acc[0][2] += a.x * b.z; acc[0][3] += a.x * b.w;
            acc[1][0] += a.y * b.x; acc[1][1] += a.y * b.y; acc[1][2] += a.y * b.z; acc[1][3] += a.y * b.w;
            acc[2][0] += a.z * b.x; acc[2][1] += a.z * b.y; acc[2][2] += a.z * b.z; acc[2][3] += a.z * b.w;
            acc[3][0] += a.w * b.x; acc[3][1] += a.w * b.y; acc[3][2] += a.w * b.z; acc[3][3] += a.w * b.w;
        }
        __syncthreads();
    }

#pragma unroll
    for (int i = 0; i < 4; ++i) {
        const int r = row0 + ty4 + i;
        if (r >= M) continue;
        float* crow = C + (size_t)r * N + col0 + tx4;
#pragma unroll
        for (int j = 0; j < 4; ++j) {
            float v = acc[i][j];
            if (bias) v += bias[col0 + tx4 + j];
            if (act == 1)  // exact GELU
                v = v * 0.5f * (1.f + erff(v * 0.70710678118654752f));
            if (beta) crow[j] += v; else crow[j] = v;
        }
    }
}

// ---------------------------------------------------------------------------
// LayerNorm over rows of 768: y = (x-mean)/sqrt(var+eps)*s + b
// one 256-thread block per row
// ---------------------------------------------------------------------------
__global__ __launch_bounds__(256) void ln_kernel(
    const float* __restrict__ x, const float* __restrict__ sc,
    const float* __restrict__ bi, float* __restrict__ y)
{
    const int row = blockIdx.x;
    const int tid = threadIdx.x;
    const float* xr = x + (size_t)row * D_;
    const float v0 = xr[tid], v1 = xr[tid + 256], v2 = xr[tid + 512];

    float s = v0 + v1 + v2;
    float q = v0 * v0 + v1 * v1 + v2 * v2;
#pragma unroll
    for (int off = 32; off > 0; off >>= 1) {
        s += __shfl_down(s, off, 64);
        q += __shfl_down(q, off, 64);
    }
    __shared__ float redS[4], redQ[4];
    if ((tid & 63) == 0) { redS[tid >> 6] = s; redQ[tid >> 6] = q; }
    __syncthreads();
    const float S = redS[0] + redS[1] + redS[2] + redS[3];
    const float Q = redQ[0] + redQ[1] + redQ[2] + redQ[3];
    const float mean = S * (1.f / D_);
    const float var  = Q * (1.f / D_) - mean * mean;
    const float inv  = rsqrtf(var + EPS_);

    float* yr = y + (size_t)row * D_;
    yr[tid]       = (v0 - mean) * inv * sc[tid]       + bi[tid];
    yr[tid + 256] = (v1 - mean) * inv * sc[tid + 256] + bi[tid + 256];
    yr[tid + 512] = (v2 - mean) * inv * sc[tid + 512] + bi[tid + 512];
}

// ---------------------------------------------------------------------------
// Attention: one 64-thread block per (b, h, q-row). Two-pass softmax with
// scores in LDS; O accumulated directly into residual z (disjoint d-slices).
// qkv layout: qkv[(b*SEQ+t)*2304 + h*192 + d*3 + {0:q,1:k,2:v}]
// ---------------------------------------------------------------------------
__global__ __launch_bounds__(64) void attn_kernel(
    const float* __restrict__ qkv, float* __restrict__ z)
{
    const int idx = blockIdx.x;
    const int t   = idx % SEQ_;
    const int h   = (idx / SEQ_) % NH_;
    const int b   = idx / (SEQ_ * NH_);
    const int lane = threadIdx.x;

    __shared__ float qs[DH_];
    __shared__ float scs[SEQ_];

    const float* qkvb = qkv + (size_t)b * SEQ_ * (3 * D_) + h * (DH_ * 3);
    qs[lane] = qkvb[(size_t)t * (3 * D_) + lane * 3 + 0];
    __syncthreads();

    float lmax = -INFINITY;
    for (int j = lane; j < SEQ_; j += 64) {
        const float* kr = qkvb + (size_t)j * (3 * D_) + 1;
        float d = 0.f;
#pragma unroll
        for (int dd = 0; dd < DH_; ++dd) d += qs[dd] * kr[dd * 3];
        d *= 0.125f;   // 1/sqrt(64)
        scs[j] = d;
        lmax = fmaxf(lmax, d);
    }
#pragma unroll
    for (int off = 32; off > 0; off >>= 1)
        lmax = fmaxf(lmax, __shfl_down(lmax, off, 64));
    lmax = __shfl(lmax, 0, 64);
    __syncthreads();

    float lsum = 0.f;
    for (int j = lane; j < SEQ_; j += 64) {
        const float e = expf(scs[j] - lmax);
        scs[j] = e;
        lsum += e;
    }
#pragma unroll
    for (int off = 32; off > 0; off >>= 1)
        lsum += __shfl_down(lsum, off, 64);
    lsum = __shfl(lsum, 0, 64);
    const float inv = 1.f / lsum;
    __syncthreads();

    // lane owns output dim d = lane
    float o = 0.f;
    const float* vr = qkvb + lane * 3 + 2;
    for (int j = 0; j < SEQ_; ++j)
        o += scs[j] * vr[(size_t)j * (3 * D_)];
    z[(size_t)(b * SEQ_ + t) * D_ + h * DH_ + lane] += o * inv;
}

// ---------------------------------------------------------------------------
// Assemble z = pos + concat(st, s2) + concat(cls, e1)
// ---------------------------------------------------------------------------
__global__ __launch_bounds__(256) void assemble_kernel(
    const float* __restrict__ P1, const float* __restrict__ P2,
    const float* __restrict__ cls, const float* __restrict__ pos,
    const float* __restrict__ st, float* __restrict__ z)
{
    const int i = blockIdx.x * 256 + threadIdx.x;  // TOK_*D_ = 6303744 = 24624*256
    const int d  = i % D_;
    const int bt = i / D_;
    const int t  = bt % SEQ_;
    const int b  = bt / SEQ_;
    float v = pos[t * D_ + d];
    v += (t < NST_) ? st[t * D_ + d]
                    : P2[((size_t)b * NSP_ + (t - NST_)) * D_ + d];
    v += (t == 0) ? cls[d]
                  : P1[((size_t)b * NPATCH_ + (t - 1)) * D_ + d];
    z[i] = v;
}

// ---------------------------------------------------------------------------
// Mean-pool over seq: y[b,d] = mean_t z[b,t,d]
// ---------------------------------------------------------------------------
__global__ __launch_bounds__(256) void pool_kernel(
    const float* __restrict__ z, float* __restrict__ y)
{
    const int i = blockIdx.x * 256 + threadIdx.x;  // B_*D_ = 12288
    const int b = i / D_, d = i % D_;
    const float* p = z + (size_t)b * SEQ_ * D_ + d;
    float s = 0.f;
    for (int t = 0; t < SEQ_; ++t) s += p[(size_t)t * D_];
    y[i] = s * (1.f / SEQ_);
}

// ---------------------------------------------------------------------------
// Head: LN(y) @ h1 + b1 -> @ h2 + b2 -> @ h3 + b3. One block per batch.
// ---------------------------------------------------------------------------
__global__ __launch_bounds__(256) void head_kernel(
    const float* __restrict__ y,
    const float* __restrict__ hn_s, const float* __restrict__ hn_b,
    const float* __restrict__ h1w, const float* __restrict__ h1b,
    const float* __restrict__ h2w, const float* __restrict__ h2b,
    const float* __restrict__ h3w, const float* __restrict__ h3b,
    float* __restrict__ out)
{
    const int b = blockIdx.x;
    const int tid = threadIdx.x;
    __shared__ float xn[D_];
    __shared__ float a1[256];
    __shared__ float a2[64];
    __shared__ float redS[4], redQ[4];

    const float* yr = y + (size_t)b * D_;
    const float v0 = yr[tid], v1 = yr[tid + 256], v2 = yr[tid + 512];
    float s = v0 + v1 + v2;
    float q = v0 * v0 + v1 * v1 + v2 * v2;
#pragma unroll
    for (int off = 32; off > 0; off >>= 1) {
        s += __shfl_down(s, off, 64);
        q += __shfl_down(q, off, 64);
    }
    if ((tid & 63) == 0) { redS[tid >> 6] = s; redQ[tid >> 6] = q; }
    __syncthreads();
    const float S = redS[0] + redS[1] + redS[2] + redS[3];
    const float Q = redQ[0] + redQ[1] + redQ[2] + redQ[3];
    const float mean = S * (1.f / D_);
    const float var  = Q * (1.f / D_) - mean * mean;
    const float inv  = rsqrtf(var + EPS_);
    xn[tid]       = (v0 - mean) * inv * hn_s[tid]       + hn_b[tid];
    xn[tid + 256] = (v1 - mean) * inv * hn_s[tid + 256] + hn_b[tid + 256];
    xn[tid + 512] = (v2 - mean) * inv * hn_s[tid + 512] + hn_b[tid + 512];
    __syncthreads();

    // h1: [768,256]
    float s1 = h1b[tid];
    for (int k = 0; k < D_; ++k) s1 += xn[k] * h1w[k * 256 + tid];
    a1[tid] = s1;
    __syncthreads();

    if (tid < 64) {
        float s2 = h2b[tid];
        for (int k = 0; k < 256; ++k) s2 += a1[k] * h2w[k * 64 + tid];
        a2[tid] = s2;
    }
    __syncthreads();

    if (tid < 64) {
        float s3 = a2[tid] * h3w[tid];
#pragma unroll
        for (int off = 32; off > 0; off >>= 1)
            s3 += __shfl_down(s3, off, 64);
        if (tid == 0) out[b] = s3 + h3b[0];
    }
}

// ---------------------------------------------------------------------------
extern "C" void kernel_launch(void* const* d_in, const int* in_sizes, int n_in,
                              void* d_out, int out_size, void* d_ws, size_t ws_size,
                              hipStream_t stream)
{
    const float* input1    = (const float*)d_in[0];
    const float* input2    = (const float*)d_in[1];
    const float* proj_w    = (const float*)d_in[2];
    const float* proj_b    = (const float*)d_in[3];
    const float* cls_token = (const float*)d_in[4];
    const float* pos_emb   = (const float*)d_in[5];
    const float* strain    = (const float*)d_in[6];
    const float* ln1_s     = (const float*)d_in[7];
    const float* ln1_b     = (const float*)d_in[8];
    const float* wqkv      = (const float*)d_in[9];
    const float* ln2_s     = (const float*)d_in[10];
    const float* ln2_b     = (const float*)d_in[11];
    const float* fc1_w     = (const float*)d_in[12];
    const float* fc1_b     = (const float*)d_in[13];
    const float* fc2_w     = (const float*)d_in[14];
    const float* fc2_b     = (const float*)d_in[15];
    const float* hn_s      = (const float*)d_in[16];
    const float* hn_b      = (const float*)d_in[17];
    const float* h1_w      = (const float*)d_in[18];
    const float* h1_b      = (const float*)d_in[19];
    const float* h2_w      = (const float*)d_in[20];
    const float* h2_b      = (const float*)d_in[21];
    const float* h3_w      = (const float*)d_in[22];
    const float* h3_b      = (const float*)d_in[23];
    float* out = (float*)d_out;
    (void)in_sizes; (void)n_in; (void)out_size; (void)ws_size;

    // workspace layout (floats):
    //   z    : TOK_*D_        =  6,303,744
    //   lnb  : TOK_*D_        =  6,303,744   (also pooled [16,768] at head)
    //   qkv  : TOK_*3*D_      = 18,911,232   (P1/P2 during embed)
    //   ffb overlaps qkv (dead after attention) + extra TOK_*D_ tail
    // total = 3*TOK_*D_ + TOK_*3D_ = 37,822,464 floats = 151.3 MB
    float* ws  = (float*)d_ws;
    float* z   = ws;
    float* lnb = z   + (size_t)TOK_ * D_;
    float* qkv = lnb + (size_t)TOK_ * D_;
    float* ffb = qkv;                                // 25,214,976 floats
    float* P1  = qkv;                                // 16*512*768
    float* P2  = qkv + (size_t)B_ * NPATCH_ * D_;    // 16*128*768

    // 1) patch projections
    gemm_f32<<<dim3(D_ / BN, (B_ * NPATCH_) / BM), 256, 0, stream>>>(
        input1, proj_w, proj_b, P1, B_ * NPATCH_, D_, 256, 0, 0);
    gemm_f32<<<dim3(D_ / BN, (B_ * NSP_) / BM), 256, 0, stream>>>(
        input2, proj_w, proj_b, P2, B_ * NSP_, D_, 256, 0, 0);

    // 2) assemble embeddings
    assemble_kernel<<<(TOK_ * D_) / 256, 256, 0, stream>>>(
        P1, P2, cls_token, pos_emb, strain, z);

    // 3) transformer layers
    const int mty = (TOK_ + BM - 1) / BM;   // 129
    for (int l = 0; l < L_; ++l) {
        ln_kernel<<<TOK_, 256, 0, stream>>>(z, ln1_s + l * D_, ln1_b + l * D_, lnb);
        gemm_f32<<<dim3((3 * D_) / BN, mty), 256, 0, stream>>>(
            lnb, wqkv + (size_t)l * D_ * 3 * D_, nullptr, qkv,
            TOK_, 3 * D_, D_, 0, 0);
        attn_kernel<<<B_ * NH_ * SEQ_, 64, 0, stream>>>(qkv, z);
        ln_kernel<<<TOK_, 256, 0, stream>>>(z, ln2_s + l * D_, ln2_b + l * D_, lnb);
        gemm_f32<<<dim3(FF_ / BN, mty), 256, 0, stream>>>(
            lnb, fc1_w + (size_t)l * D_ * FF_, fc1_b + l * FF_, ffb,
            TOK_, FF_, D_, 1, 0);
        gemm_f32<<<dim3(D_ / BN, mty), 256, 0, stream>>>(
            ffb, fc2_w + (size_t)l * FF_ * D_, fc2_b + l * D_, z,
            TOK_, D_, FF_, 0, 1);
    }

    // 4) head
    pool_kernel<<<(B_ * D_) / 256, 256, 0, stream>>>(z, lnb);
    head_kernel<<<B_, 256, 0, stream>>>(lnb, hn_s, hn_b,
        h1_w, h1_b, h2_w, h2_b, h3_w, h3_b, out);
}

// Round 2
// 23207.837 us; speedup vs baseline: 4.4403x; 4.4403x over previous
//
#include <hip/hip_runtime.h>
#include <math.h>

#define B_      16
#define SEQ_    513
#define D_      768
#define NH_     12
#define DH_     64
#define L_      12
#define FF_     3072
#define NPATCH_ 512
#define NSP_    128
#define NST_    385            // NPATCH - NSP + 1
#define TOK_    (B_ * SEQ_)    // 8208
#define EPS_    1e-5f

// ---------------------------------------------------------------------------
// Generic fp32 tiled GEMM: C[M,N] = act(A[M,K] @ B[K,N] + bias) (+= if beta)
// BM=BN=64, BK=16, 256 threads, 4x4 per-thread microtile.
// scatter=1: write output into Q/K/V planes [3][B,NH,SEQ,DH] (for the QKV gemm)
// ---------------------------------------------------------------------------
#define BM 64
#define BN 64
#define BK 16

__global__ __launch_bounds__(256) void gemm_f32(
    const float* __restrict__ A, const float* __restrict__ Bm,
    const float* __restrict__ bias, float* __restrict__ C,
    int M, int N, int K, int act, int beta, int scatter)
{
    __shared__ float As[BK][BM];
    __shared__ float Bs[BK][BN];
    const int tid  = threadIdx.x;
    const int row0 = blockIdx.y * BM;
    const int col0 = blockIdx.x * BN;
    const int ty4  = (tid >> 4) * 4;   // 0..60
    const int tx4  = (tid & 15) * 4;   // 0..60

    const int la   = tid * 4;
    const int arow = la >> 4;          // 0..63
    const int ak   = la & 15;          // 0,4,8,12
    const int brow = la >> 6;          // 0..15
    const int bcol = la & 63;

    float acc[4][4] = {};

    for (int k0 = 0; k0 < K; k0 += BK) {
        float4 av;
        if (row0 + arow < M)
            av = *(const float4*)(A + (size_t)(row0 + arow) * K + k0 + ak);
        else
            av = make_float4(0.f, 0.f, 0.f, 0.f);
        As[ak + 0][arow] = av.x;
        As[ak + 1][arow] = av.y;
        As[ak + 2][arow] = av.z;
        As[ak + 3][arow] = av.w;

        float4 bv = *(const float4*)(Bm + (size_t)(k0 + brow) * N + col0 + bcol);
        *(float4*)&Bs[brow][bcol] = bv;

        __syncthreads();
#pragma unroll
        for (int k = 0; k < BK; ++k) {
            const float4 a = *(const float4*)&As[k][ty4];
            const float4 b = *(const float4*)&Bs[k][tx4];
            acc[0][0] += a.x * b.x; acc[0][1] += a.x * b.y; acc[0][2] += a.x * b.z; acc[0][3] += a.x * b.w;
            acc[1][0] += a.y * b.x; acc[1][1] += a.y * b.y; acc[1][2] += a.y * b.z; acc[1][3] += a.y * b.w;
            acc[2][0] += a.z * b.x; acc[2][1] += a.z * b.y; acc[2][2] += a.z * b.z; acc[2][3] += a.z * b.w;
            acc[3][0] += a.w * b.x; acc[3][1] += a.w * b.y; acc[3][2] += a.w * b.z; acc[3][3] += a.w * b.w;
        }
        __syncthreads();
    }

    if (scatter) {
        // QKV scatter: column c = h*192 + d*3 + s  ->  plane s, [b,h,t,d]
#pragma unroll
        for (int i = 0; i < 4; ++i) {
            const int r = row0 + ty4 + i;
            if (r >= M) continue;
            const int b = r / SEQ_;
            const int t = r - b * SEQ_;
#pragma unroll
            for (int j = 0; j < 4; ++j) {
                const int c   = col0 + tx4 + j;
                const int h   = c / 192;
                const int rem = c - h * 192;
                const int d   = rem / 3;
                const int s   = rem - d * 3;
                C[(size_t)s * ((size_t)TOK_ * D_) +
                  (((size_t)b * NH_ + h) * SEQ_ + t) * DH_ + d] = acc[i][j];
            }
        }
        return;
    }

#pragma unroll
    for (int i = 0; i < 4; ++i) {
        const int r = row0 + ty4 + i;
        if (r >= M) continue;
        float* crow = C + (size_t)r * N + col0 + tx4;
#pragma unroll
        for (int j = 0; j < 4; ++j) {
            float v = acc[i][j];
            if (bias) v += bias[col0 + tx4 + j];
            if (act == 1)  // exact GELU
                v = v * 0.5f * (1.f + erff(v * 0.70710678118654752f));
            if (beta) crow[j] += v; else crow[j] = v;
        }
    }
}

// ---------------------------------------------------------------------------
// LayerNorm over rows of 768
// ---------------------------------------------------------------------------
__global__ __launch_bounds__(256) void ln_kernel(
    const float* __restrict__ x, const float* __restrict__ sc,
    const float* __restrict__ bi, float* __restrict__ y)
{
    const int row = blockIdx.x;
    const int tid = threadIdx.x;
    const float* xr = x + (size_t)row * D_;
    const float v0 = xr[tid], v1 = xr[tid + 256], v2 = xr[tid + 512];

    float s = v0 + v1 + v2;
    float q = v0 * v0 + v1 * v1 + v2 * v2;
#pragma unroll
    for (int off = 32; off > 0; off >>= 1) {
        s += __shfl_down(s, off, 64);
        q += __shfl_down(q, off, 64);
    }
    __shared__ float redS[4], redQ[4];
    if ((tid & 63) == 0) { redS[tid >> 6] = s; redQ[tid >> 6] = q; }
    __syncthreads();
    const float S = redS[0] + redS[1] + redS[2] + redS[3];
    const float Q = redQ[0] + redQ[1] + redQ[2] + redQ[3];
    const float mean = S * (1.f / D_);
    const float var  = Q * (1.f / D_) - mean * mean;
    const float inv  = rsqrtf(var + EPS_);

    float* yr = y + (size_t)row * D_;
    yr[tid]       = (v0 - mean) * inv * sc[tid]       + bi[tid];
    yr[tid + 256] = (v1 - mean) * inv * sc[tid + 256] + bi[tid + 256];
    yr[tid + 512] = (v2 - mean) * inv * sc[tid + 512] + bi[tid + 512];
}

// ---------------------------------------------------------------------------
// Flash-style attention. Grid: (qtile=9, b*h=192). Block 256.
// Q/K/V planes: [B,NH,SEQ,DH] each (contiguous, stride TOK_*D_ between planes).
// O accumulated in registers (4x4/thread), online softmax, z += O/l.
// ---------------------------------------------------------------------------
#define TQ 64
#define TK 64

__global__ __launch_bounds__(256) void attn_kernel(
    const float* __restrict__ qkvp, float* __restrict__ z)
{
    __shared__ float Qt[DH_][TQ];      // [d][r]   (transposed)
    __shared__ float KVs[DH_][TK];     // K phase: [d][j]; V phase: [j][d]
    __shared__ float Pt[TK][68];       // [j][r]  (pad 68 to spread banks)
    __shared__ float pmax[16][TQ];
    __shared__ float psum[4][TQ];
    __shared__ float mrow[TQ], arow[TQ];

    const int tid = threadIdx.x;
    const int q0  = blockIdx.x * TQ;
    const int bh  = blockIdx.y;
    const int ty4 = (tid >> 4) << 2;
    const int tx4 = (tid & 15) << 2;
    const int dj  = (tid & 15) * 4;    // loader: dim offset
    const int r0  = tid >> 4;          // loader: row 0..15

    const float* Qg = qkvp + (size_t)bh * SEQ_ * DH_;
    const float* Kg = Qg + (size_t)TOK_ * D_;
    const float* Vg = Kg + (size_t)TOK_ * D_;

    // load Q tile transposed
#pragma unroll
    for (int rr = 0; rr < TQ; rr += 16) {
        const int r = rr + r0;
        const int t = q0 + r;
        float4 v = make_float4(0.f, 0.f, 0.f, 0.f);
        if (t < SEQ_) v = *(const float4*)(Qg + (size_t)t * DH_ + dj);
        Qt[dj + 0][r] = v.x; Qt[dj + 1][r] = v.y;
        Qt[dj + 2][r] = v.z; Qt[dj + 3][r] = v.w;
    }

    float acc_o[4][4] = {};
    float m_i = -INFINITY, l_i = 0.f;   // live in tid<64 only

    const int nt = (SEQ_ + TK - 1) / TK;  // 9
    for (int kt = 0; kt < nt; ++kt) {
        const int k0 = kt * TK;

        // ---- load K tile transposed into KVs[d][j] ----
#pragma unroll
        for (int rr = 0; rr < TK; rr += 16) {
            const int j = rr + r0;
            const int t = k0 + j;
            float4 kv = make_float4(0.f, 0.f, 0.f, 0.f);
            if (t < SEQ_) kv = *(const float4*)(Kg + (size_t)t * DH_ + dj);
            KVs[dj + 0][j] = kv.x; KVs[dj + 1][j] = kv.y;
            KVs[dj + 2][j] = kv.z; KVs[dj + 3][j] = kv.w;
        }
        __syncthreads();

        // ---- S = (Q K^T) * 1/8 ----
        float acc[4][4] = {};
#pragma unroll
        for (int d = 0; d < DH_; ++d) {
            const float4 a = *(const float4*)&Qt[d][ty4];
            const float4 b = *(const float4*)&KVs[d][tx4];
            acc[0][0] += a.x * b.x; acc[0][1] += a.x * b.y; acc[0][2] += a.x * b.z; acc[0][3] += a.x * b.w;
            acc[1][0] += a.y * b.x; acc[1][1] += a.y * b.y; acc[1][2] += a.y * b.z; acc[1][3] += a.y * b.w;
            acc[2][0] += a.z * b.x; acc[2][1] += a.z * b.y; acc[2][2] += a.z * b.z; acc[2][3] += a.z * b.w;
            acc[3][0] += a.w * b.x; acc[3][1] += a.w * b.y; acc[3][2] += a.w * b.z; acc[3][3] += a.w * b.w;
        }
        // write scaled+masked scores to Pt, per-thread row maxes to pmax
#pragma unroll
        for (int i = 0; i < 4; ++i) {
            float tmax = -INFINITY;
#pragma unroll
            for (int j = 0; j < 4; ++j) {
                float sv = acc[i][j] * 0.125f;
                if (k0 + tx4 + j >= SEQ_) sv = -INFINITY;
                Pt[tx4 + j][ty4 + i] = sv;
                tmax = fmaxf(tmax, sv);
            }
            pmax[tid & 15][ty4 + i] = tmax;
        }
        __syncthreads();

        // ---- prefetch V into regs; rows: new max + alpha ----
        float4 vreg[4];
#pragma unroll
        for (int rr = 0; rr < 4; ++rr) {
            const int j = rr * 16 + r0;
            const int t = k0 + j;
            vreg[rr] = make_float4(0.f, 0.f, 0.f, 0.f);
            if (t < SEQ_) vreg[rr] = *(const float4*)(Vg + (size_t)t * DH_ + dj);
        }
        if (tid < TQ) {
            float mt = pmax[0][tid];
#pragma unroll
            for (int g = 1; g < 16; ++g) mt = fmaxf(mt, pmax[g][tid]);
            const float mnew = fmaxf(m_i, mt);
            arow[tid] = expf(m_i - mnew);
            mrow[tid] = mnew;
            m_i = mnew;
        }
        __syncthreads();

        // ---- V -> LDS (KVs now [j][d]); exp pass on Pt ----
#pragma unroll
        for (int rr = 0; rr < 4; ++rr) {
            const int j = rr * 16 + r0;
            *(float4*)&KVs[j][dj] = vreg[rr];
        }
        {
            const int r = tid & 63;
            const int g = tid >> 6;
            const float mr = mrow[r];
            float ps = 0.f;
#pragma unroll
            for (int jj = 0; jj < 16; ++jj) {
                const int j = g * 16 + jj;
                const float p = expf(Pt[j][r] - mr);
                Pt[j][r] = p;
                ps += p;
            }
            psum[g][r] = ps;
        }
        __syncthreads();

        if (tid < TQ)
            l_i = l_i * arow[tid] + psum[0][tid] + psum[1][tid] + psum[2][tid] + psum[3][tid];

        // ---- rescale O; O += P V ----
#pragma unroll
        for (int i = 0; i < 4; ++i) {
            const float a = arow[ty4 + i];
            acc_o[i][0] *= a; acc_o[i][1] *= a; acc_o[i][2] *= a; acc_o[i][3] *= a;
        }
#pragma unroll
        for (int j = 0; j < TK; ++j) {
            const float4 p = *(const float4*)&Pt[j][ty4];
            const float4 v = *(const float4*)&KVs[j][tx4];
            acc_o[0][0] += p.x * v.x; acc_o[0][1] += p.x * v.y; acc_o[0][2] += p.x * v.z; acc_o[0][3] += p.x * v.w;
            acc_o[1][0] += p.y * v.x; acc_o[1][1] += p.y * v.y; acc_o[1][2] += p.y * v.z; acc_o[1][3] += p.y * v.w;
            acc_o[2][0] += p.z * v.x; acc_o[2][1] += p.z * v.y; acc_o[2][2] += p.z * v.z; acc_o[2][3] += p.z * v.w;
            acc_o[3][0] += p.w * v.x; acc_o[3][1] += p.w * v.y; acc_o[3][2] += p.w * v.z; acc_o[3][3] += p.w * v.w;
        }
        __syncthreads();
    }

    if (tid < TQ) arow[tid] = 1.f / l_i;
    __syncthreads();

    const int h = bh % NH_;
    const int b = bh / NH_;
#pragma unroll
    for (int i = 0; i < 4; ++i) {
        const int t = q0 + ty4 + i;
        if (t >= SEQ_) continue;
        const float inv = arow[ty4 + i];
        float* zp = z + ((size_t)b * SEQ_ + t) * D_ + h * DH_ + tx4;
        float4 o = *(const float4*)zp;
        o.x += acc_o[i][0] * inv;
        o.y += acc_o[i][1] * inv;
        o.z += acc_o[i][2] * inv;
        o.w += acc_o[i][3] * inv;
        *(float4*)zp = o;
    }
}

// ---------------------------------------------------------------------------
// Assemble z = pos + concat(st, s2) + concat(cls, e1)
// ---------------------------------------------------------------------------
__global__ __launch_bounds__(256) void assemble_kernel(
    const float* __restrict__ P1, const float* __restrict__ P2,
    const float* __restrict__ cls, const float* __restrict__ pos,
    const float* __restrict__ st, float* __restrict__ z)
{
    const int i = blockIdx.x * 256 + threadIdx.x;
    const int d  = i % D_;
    const int bt = i / D_;
    const int t  = bt % SEQ_;
    const int b  = bt / SEQ_;
    float v = pos[t * D_ + d];
    v += (t < NST_) ? st[t * D_ + d]
                    : P2[((size_t)b * NSP_ + (t - NST_)) * D_ + d];
    v += (t == 0) ? cls[d]
                  : P1[((size_t)b * NPATCH_ + (t - 1)) * D_ + d];
    z[i] = v;
}

// ---------------------------------------------------------------------------
__global__ __launch_bounds__(256) void pool_kernel(
    const float* __restrict__ z, float* __restrict__ y)
{
    const int i = blockIdx.x * 256 + threadIdx.x;  // B_*D_
    const int b = i / D_, d = i % D_;
    const float* p = z + (size_t)b * SEQ_ * D_ + d;
    float s = 0.f;
    for (int t = 0; t < SEQ_; ++t) s += p[(size_t)t * D_];
    y[i] = s * (1.f / SEQ_);
}

// ---------------------------------------------------------------------------
__global__ __launch_bounds__(256) void head_kernel(
    const float* __restrict__ y,
    const float* __restrict__ hn_s, const float* __restrict__ hn_b,
    const float* __restrict__ h1w, const float* __restrict__ h1b,
    const float* __restrict__ h2w, const float* __restrict__ h2b,
    const float* __restrict__ h3w, const float* __restrict__ h3b,
    float* __restrict__ out)
{
    const int b = blockIdx.x;
    const int tid = threadIdx.x;
    __shared__ float xn[D_];
    __shared__ float a1[256];
    __shared__ float a2[64];
    __shared__ float redS[4], redQ[4];

    const float* yr = y + (size_t)b * D_;
    const float v0 = yr[tid], v1 = yr[tid + 256], v2 = yr[tid + 512];
    float s = v0 + v1 + v2;
    float q = v0 * v0 + v1 * v1 + v2 * v2;
#pragma unroll
    for (int off = 32; off > 0; off >>= 1) {
        s += __shfl_down(s, off, 64);
        q += __shfl_down(q, off, 64);
    }
    if ((tid & 63) == 0) { redS[tid >> 6] = s; redQ[tid >> 6] = q; }
    __syncthreads();
    const float S = redS[0] + redS[1] + redS[2] + redS[3];
    const float Q = redQ[0] + redQ[1] + redQ[2] + redQ[3];
    const float mean = S * (1.f / D_);
    const float var  = Q * (1.f / D_) - mean * mean;
    const float inv  = rsqrtf(var + EPS_);
    xn[tid]       = (v0 - mean) * inv * hn_s[tid]       + hn_b[tid];
    xn[tid + 256] = (v1 - mean) * inv * hn_s[tid + 256] + hn_b[tid + 256];
    xn[tid + 512] = (v2 - mean) * inv * hn_s[tid + 512] + hn_b[tid + 512];
    __syncthreads();

    float s1 = h1b[tid];
    for (int k = 0; k < D_; ++k) s1 += xn[k] * h1w[k * 256 + tid];
    a1[tid] = s1;
    __syncthreads();

    if (tid < 64) {
        float s2 = h2b[tid];
        for (int k = 0; k < 256; ++k) s2 += a1[k] * h2w[k * 64 + tid];
        a2[tid] = s2;
    }
    __syncthreads();

    if (tid < 64) {
        float s3 = a2[tid] * h3w[tid];
#pragma unroll
        for (int off = 32; off > 0; off >>= 1)
            s3 += __shfl_down(s3, off, 64);
        if (tid == 0) out[b] = s3 + h3b[0];
    }
}

// ---------------------------------------------------------------------------
extern "C" void kernel_launch(void* const* d_in, const int* in_sizes, int n_in,
                              void* d_out, int out_size, void* d_ws, size_t ws_size,
                              hipStream_t stream)
{
    const float* input1    = (const float*)d_in[0];
    const float* input2    = (const float*)d_in[1];
    const float* proj_w    = (const float*)d_in[2];
    const float* proj_b    = (const float*)d_in[3];
    const float* cls_token = (const float*)d_in[4];
    const float* pos_emb   = (const float*)d_in[5];
    const float* strain    = (const float*)d_in[6];
    const float* ln1_s     = (const float*)d_in[7];
    const float* ln1_b     = (const float*)d_in[8];
    const float* wqkv      = (const float*)d_in[9];
    const float* ln2_s     = (const float*)d_in[10];
    const float* ln2_b     = (const float*)d_in[11];
    const float* fc1_w     = (const float*)d_in[12];
    const float* fc1_b     = (const float*)d_in[13];
    const float* fc2_w     = (const float*)d_in[14];
    const float* fc2_b     = (const float*)d_in[15];
    const float* hn_s      = (const float*)d_in[16];
    const float* hn_b      = (const float*)d_in[17];
    const float* h1_w      = (const float*)d_in[18];
    const float* h1_b      = (const float*)d_in[19];
    const float* h2_w      = (const float*)d_in[20];
    const float* h2_b      = (const float*)d_in[21];
    const float* h3_w      = (const float*)d_in[22];
    const float* h3_b      = (const float*)d_in[23];
    float* out = (float*)d_out;
    (void)in_sizes; (void)n_in; (void)out_size; (void)ws_size;

    // workspace layout (floats): z | lnb | qkv planes (Q,K,V each TOK_*D_)
    // ffb overlaps qkv (dead after attention) + tail; total 151.3 MB
    float* ws  = (float*)d_ws;
    float* z   = ws;
    float* lnb = z   + (size_t)TOK_ * D_;
    float* qkv = lnb + (size_t)TOK_ * D_;
    float* ffb = qkv;
    float* P1  = qkv;
    float* P2  = qkv + (size_t)B_ * NPATCH_ * D_;

    // 1) patch projections
    gemm_f32<<<dim3(D_ / BN, (B_ * NPATCH_) / BM), 256, 0, stream>>>(
        input1, proj_w, proj_b, P1, B_ * NPATCH_, D_, 256, 0, 0, 0);
    gemm_f32<<<dim3(D_ / BN, (B_ * NSP_) / BM), 256, 0, stream>>>(
        input2, proj_w, proj_b, P2, B_ * NSP_, D_, 256, 0, 0, 0);

    // 2) assemble embeddings
    assemble_kernel<<<(TOK_ * D_) / 256, 256, 0, stream>>>(
        P1, P2, cls_token, pos_emb, strain, z);

    // 3) transformer layers
    const int mty = (TOK_ + BM - 1) / BM;   // 129
    const int qtiles = (SEQ_ + TQ - 1) / TQ; // 9
    for (int l = 0; l < L_; ++l) {
        ln_kernel<<<TOK_, 256, 0, stream>>>(z, ln1_s + l * D_, ln1_b + l * D_, lnb);
        gemm_f32<<<dim3((3 * D_) / BN, mty), 256, 0, stream>>>(
            lnb, wqkv + (size_t)l * D_ * 3 * D_, nullptr, qkv,
            TOK_, 3 * D_, D_, 0, 0, 1);
        attn_kernel<<<dim3(qtiles, B_ * NH_), 256, 0, stream>>>(qkv, z);
        ln_kernel<<<TOK_, 256, 0, stream>>>(z, ln2_s + l * D_, ln2_b + l * D_, lnb);
        gemm_f32<<<dim3(FF_ / BN, mty), 256, 0, stream>>>(
            lnb, fc1_w + (size_t)l * D_ * FF_, fc1_b + l * FF_, ffb,
            TOK_, FF_, D_, 1, 0, 0);
        gemm_f32<<<dim3(D_ / BN, mty), 256, 0, stream>>>(
            ffb, fc2_w + (size_t)l * FF_ * D_, fc2_b + l * D_, z,
            TOK_, D_, FF_, 0, 1, 0);
    }

    // 4) head
    pool_kernel<<<(B_ * D_) / 256, 256, 0, stream>>>(z, lnb);
    head_kernel<<<B_, 256, 0, stream>>>(lnb, hn_s, hn_b,
        h1_w, h1_b, h2_w, h2_b, h3_w, h3_b, out);
}

// Round 3
// 10336.346 us; speedup vs baseline: 9.9697x; 2.2453x over previous
//
#include <hip/hip_runtime.h>
#include <math.h>

#define B_      16
#define SEQ_    513
#define D_      768
#define NH_     12
#define DH_     64
#define L_      12
#define FF_     3072
#define NPATCH_ 512
#define NSP_    128
#define NST_    385            // NPATCH - NSP + 1
#define TOK_    (B_ * SEQ_)    // 8208
#define EPS_    1e-5f

typedef unsigned short ushortT;
typedef unsigned int   uintT;
typedef __attribute__((ext_vector_type(8))) short short8;
typedef __attribute__((ext_vector_type(4))) float floatx4;

__device__ __forceinline__ ushortT f2bf(float x) {
    uintT u = __float_as_uint(x);
    u += 0x7FFF + ((u >> 16) & 1);           // round-to-nearest-even
    return (ushortT)(u >> 16);
}
__device__ __forceinline__ float bf2f(ushortT h) {
    return __uint_as_float(((uintT)h) << 16);
}

// ---------------------------------------------------------------------------
// fp32 tiled GEMM (patch embedding only). BM=BN=64, BK=16.
// ---------------------------------------------------------------------------
#define BM 64
#define BN 64
#define BK 16

__global__ __launch_bounds__(256) void gemm_f32(
    const float* __restrict__ A, const float* __restrict__ Bm,
    const float* __restrict__ bias, float* __restrict__ C,
    int M, int N, int K)
{
    __shared__ float As[BK][BM];
    __shared__ float Bs[BK][BN];
    const int tid  = threadIdx.x;
    const int row0 = blockIdx.y * BM;
    const int col0 = blockIdx.x * BN;
    const int ty4  = (tid >> 4) * 4;
    const int tx4  = (tid & 15) * 4;

    const int la   = tid * 4;
    const int arow = la >> 4;
    const int ak   = la & 15;
    const int brow = la >> 6;
    const int bcol = la & 63;

    float acc[4][4] = {};

    for (int k0 = 0; k0 < K; k0 += BK) {
        float4 av;
        if (row0 + arow < M)
            av = *(const float4*)(A + (size_t)(row0 + arow) * K + k0 + ak);
        else
            av = make_float4(0.f, 0.f, 0.f, 0.f);
        As[ak + 0][arow] = av.x;
        As[ak + 1][arow] = av.y;
        As[ak + 2][arow] = av.z;
        As[ak + 3][arow] = av.w;

        float4 bv = *(const float4*)(Bm + (size_t)(k0 + brow) * N + col0 + bcol);
        *(float4*)&Bs[brow][bcol] = bv;

        __syncthreads();
#pragma unroll
        for (int k = 0; k < BK; ++k) {
            const float4 a = *(const float4*)&As[k][ty4];
            const float4 b = *(const float4*)&Bs[k][tx4];
            acc[0][0] += a.x * b.x; acc[0][1] += a.x * b.y; acc[0][2] += a.x * b.z; acc[0][3] += a.x * b.w;
            acc[1][0] += a.y * b.x; acc[1][1] += a.y * b.y; acc[1][2] += a.y * b.z; acc[1][3] += a.y * b.w;
            acc[2][0] += a.z * b.x; acc[2][1] += a.z * b.y; acc[2][2] += a.z * b.z; acc[2][3] += a.z * b.w;
            acc[3][0] += a.w * b.x; acc[3][1] += a.w * b.y; acc[3][2] += a.w * b.z; acc[3][3] += a.w * b.w;
        }
        __syncthreads();
    }

#pragma unroll
    for (int i = 0; i < 4; ++i) {
        const int r = row0 + ty4 + i;
        if (r >= M) continue;
        float* crow = C + (size_t)r * N + col0 + tx4;
#pragma unroll
        for (int j = 0; j < 4; ++j)
            crow[j] = acc[i][j] + bias[col0 + tx4 + j];
    }
}

// ---------------------------------------------------------------------------
// Weight convert+transpose: W[K][N] fp32 -> Wt_hi[N][K], Wt_lo[N][K] bf16
// grid (N/64, K/64), 256 threads
// ---------------------------------------------------------------------------
__global__ __launch_bounds__(256) void wconv_kernel(
    const float* __restrict__ W, ushortT* __restrict__ Wh,
    ushortT* __restrict__ Wl, int N, int K)
{
    __shared__ float T[64][65];
    const int tid = threadIdx.x;
    const int n0 = blockIdx.x * 64;
    const int k0 = blockIdx.y * 64;
#pragma unroll
    for (int i = 0; i < 4; ++i) {
        const int idx = tid + 256 * i;
        const int kr = idx >> 4;
        const int nc = (idx & 15) * 4;
        float4 w = *(const float4*)(W + (size_t)(k0 + kr) * N + n0 + nc);
        T[kr][nc + 0] = w.x; T[kr][nc + 1] = w.y;
        T[kr][nc + 2] = w.z; T[kr][nc + 3] = w.w;
    }
    __syncthreads();
#pragma unroll
    for (int i = 0; i < 4; ++i) {
        const int idx = tid + 256 * i;
        const int nr = idx >> 4;
        const int kc = (idx & 15) * 4;
        uintT h01 = 0, h23 = 0, l01 = 0, l23 = 0;
#pragma unroll
        for (int j = 0; j < 4; ++j) {
            const float x = T[kc + j][nr];
            const ushortT h = f2bf(x);
            const ushortT l = f2bf(x - bf2f(h));
            if (j < 2) { h01 |= ((uintT)h) << (16 * j); l01 |= ((uintT)l) << (16 * j); }
            else       { h23 |= ((uintT)h) << (16 * (j - 2)); l23 |= ((uintT)l) << (16 * (j - 2)); }
        }
        const size_t off = (size_t)(n0 + nr) * K + k0 + kc;
        *(uint2*)(Wh + off) = make_uint2(h01, h23);
        *(uint2*)(Wl + off) = make_uint2(l01, l23);
    }
}

// ---------------------------------------------------------------------------
// bf16x3 MFMA GEMM: C = A@B, A=[M,K] via hi/lo bf16 planes (row-major),
// B via hi/lo bf16 planes TRANSPOSED [N][K]. 128x128 tile, BK=32, 4 waves.
// mode 1: scatter fp32 into Q/K/V planes (no bias)
// mode 2: bias+GELU -> bf16 hi/lo planes Ch/Cl [M][N]
// mode 3: bias, Cf[M][N] += v
// ---------------------------------------------------------------------------
#define GBM 128
#define GBN 128
#define GBK 32

__global__ __launch_bounds__(256) void mfma_gemm(
    const ushortT* __restrict__ Ah, const ushortT* __restrict__ Al,
    const ushortT* __restrict__ Bh, const ushortT* __restrict__ Bl,
    const float* __restrict__ bias, float* __restrict__ Cf,
    ushortT* __restrict__ Ch, ushortT* __restrict__ Cl,
    int M, int N, int K, int mode)
{
    __shared__ __align__(16) ushortT Ahs[GBM * GBK];
    __shared__ __align__(16) ushortT Als[GBM * GBK];
    __shared__ __align__(16) ushortT Bhs[GBN * GBK];
    __shared__ __align__(16) ushortT Bls[GBN * GBK];

    const int tid  = threadIdx.x;
    const int row0 = blockIdx.y * GBM;
    const int col0 = blockIdx.x * GBN;
    const int lane = tid & 63;
    const int wv   = tid >> 6;
    const int wr   = wv >> 1;          // wave row 0..1
    const int wc   = wv & 1;           // wave col 0..1
    const int ln15 = lane & 15;
    const int lq   = lane >> 4;        // 0..3

    floatx4 acc[4][4];
#pragma unroll
    for (int i = 0; i < 4; ++i)
#pragma unroll
        for (int j = 0; j < 4; ++j)
            acc[i][j] = (floatx4){0.f, 0.f, 0.f, 0.f};

    for (int k0 = 0; k0 < K; k0 += GBK) {
#pragma unroll
        for (int cc = 0; cc < 2; ++cc) {
            const int c  = tid + 256 * cc;      // 0..511
            const int r  = c >> 2;              // 0..127
            const int ks = (c & 3) * 8;         // 0,8,16,24
            const uint4 z4 = make_uint4(0u, 0u, 0u, 0u);
            uint4 vh = z4, vl = z4;
            if (row0 + r < M) {
                const size_t go = (size_t)(row0 + r) * K + k0 + ks;
                vh = *(const uint4*)(Ah + go);
                vl = *(const uint4*)(Al + go);
            }
            *(uint4*)&Ahs[c * 8] = vh;
            *(uint4*)&Als[c * 8] = vl;
            const size_t bo = (size_t)(col0 + r) * K + k0 + ks;
            *(uint4*)&Bhs[c * 8] = *(const uint4*)(Bh + bo);
            *(uint4*)&Bls[c * 8] = *(const uint4*)(Bl + bo);
        }
        __syncthreads();

        short8 afh[4], afl[4], bfh[4], bfl[4];
#pragma unroll
        for (int i = 0; i < 4; ++i) {
            const int ao = (wr * 64 + i * 16 + ln15) * GBK + lq * 8;
            const int bo = (wc * 64 + i * 16 + ln15) * GBK + lq * 8;
            afh[i] = *(const short8*)&Ahs[ao];
            afl[i] = *(const short8*)&Als[ao];
            bfh[i] = *(const short8*)&Bhs[bo];
            bfl[i] = *(const short8*)&Bls[bo];
        }
#pragma unroll
        for (int mi = 0; mi < 4; ++mi)
#pragma unroll
            for (int ni = 0; ni < 4; ++ni) {
                acc[mi][ni] = __builtin_amdgcn_mfma_f32_16x16x32_bf16(afh[mi], bfh[ni], acc[mi][ni], 0, 0, 0);
                acc[mi][ni] = __builtin_amdgcn_mfma_f32_16x16x32_bf16(afh[mi], bfl[ni], acc[mi][ni], 0, 0, 0);
                acc[mi][ni] = __builtin_amdgcn_mfma_f32_16x16x32_bf16(afl[mi], bfh[ni], acc[mi][ni], 0, 0, 0);
            }
        __syncthreads();
    }

    // epilogue: C row = row0+wr*64+mi*16+lq*4+reg, col = col0+wc*64+ni*16+ln15
#pragma unroll
    for (int mi = 0; mi < 4; ++mi) {
#pragma unroll
        for (int ni = 0; ni < 4; ++ni) {
            const int cg = col0 + wc * 64 + ni * 16 + ln15;
#pragma unroll
            for (int reg = 0; reg < 4; ++reg) {
                const int rg = row0 + wr * 64 + mi * 16 + lq * 4 + reg;
                if (rg >= M) continue;
                float v = acc[mi][ni][reg];
                if (mode == 1) {
                    const int b   = rg / SEQ_;
                    const int t   = rg - b * SEQ_;
                    const int h   = cg / 192;
                    const int rem = cg - h * 192;
                    const int d   = rem / 3;
                    const int s   = rem - d * 3;
                    Cf[(size_t)s * ((size_t)TOK_ * D_) +
                       (((size_t)b * NH_ + h) * SEQ_ + t) * DH_ + d] = v;
                } else if (mode == 2) {
                    v += bias[cg];
                    v = v * 0.5f * (1.f + erff(v * 0.70710678118654752f));
                    const ushortT h16 = f2bf(v);
                    const size_t off = (size_t)rg * N + cg;
                    Ch[off] = h16;
                    Cl[off] = f2bf(v - bf2f(h16));
                } else {
                    v += bias[cg];
                    Cf[(size_t)rg * N + cg] += v;
                }
            }
        }
    }
}

// ---------------------------------------------------------------------------
// LayerNorm -> bf16 hi/lo planes
// ---------------------------------------------------------------------------
__global__ __launch_bounds__(256) void ln_bf_kernel(
    const float* __restrict__ x, const float* __restrict__ sc,
    const float* __restrict__ bi, ushortT* __restrict__ yh,
    ushortT* __restrict__ yl)
{
    const int row = blockIdx.x;
    const int tid = threadIdx.x;
    const float* xr = x + (size_t)row * D_;
    const float v0 = xr[tid], v1 = xr[tid + 256], v2 = xr[tid + 512];

    float s = v0 + v1 + v2;
    float q = v0 * v0 + v1 * v1 + v2 * v2;
#pragma unroll
    for (int off = 32; off > 0; off >>= 1) {
        s += __shfl_down(s, off, 64);
        q += __shfl_down(q, off, 64);
    }
    __shared__ float redS[4], redQ[4];
    if ((tid & 63) == 0) { redS[tid >> 6] = s; redQ[tid >> 6] = q; }
    __syncthreads();
    const float S = redS[0] + redS[1] + redS[2] + redS[3];
    const float Q = redQ[0] + redQ[1] + redQ[2] + redQ[3];
    const float mean = S * (1.f / D_);
    const float var  = Q * (1.f / D_) - mean * mean;
    const float inv  = rsqrtf(var + EPS_);

    const size_t base = (size_t)row * D_;
#pragma unroll
    for (int i = 0; i < 3; ++i) {
        const int d = tid + 256 * i;
        const float vv = (i == 0 ? v0 : (i == 1 ? v1 : v2));
        const float y  = (vv - mean) * inv * sc[d] + bi[d];
        const ushortT h = f2bf(y);
        yh[base + d] = h;
        yl[base + d] = f2bf(y - bf2f(h));
    }
}

// ---------------------------------------------------------------------------
// Flash attention (unchanged from round 2)
// ---------------------------------------------------------------------------
#define TQ 64
#define TK 64

__global__ __launch_bounds__(256) void attn_kernel(
    const float* __restrict__ qkvp, float* __restrict__ z)
{
    __shared__ float Qt[DH_][TQ];
    __shared__ float KVs[DH_][TK];
    __shared__ float Pt[TK][68];
    __shared__ float pmax[16][TQ];
    __shared__ float psum[4][TQ];
    __shared__ float mrow[TQ], arow[TQ];

    const int tid = threadIdx.x;
    const int q0  = blockIdx.x * TQ;
    const int bh  = blockIdx.y;
    const int ty4 = (tid >> 4) << 2;
    const int tx4 = (tid & 15) << 2;
    const int dj  = (tid & 15) * 4;
    const int r0  = tid >> 4;

    const float* Qg = qkvp + (size_t)bh * SEQ_ * DH_;
    const float* Kg = Qg + (size_t)TOK_ * D_;
    const float* Vg = Kg + (size_t)TOK_ * D_;

#pragma unroll
    for (int rr = 0; rr < TQ; rr += 16) {
        const int r = rr + r0;
        const int t = q0 + r;
        float4 v = make_float4(0.f, 0.f, 0.f, 0.f);
        if (t < SEQ_) v = *(const float4*)(Qg + (size_t)t * DH_ + dj);
        Qt[dj + 0][r] = v.x; Qt[dj + 1][r] = v.y;
        Qt[dj + 2][r] = v.z; Qt[dj + 3][r] = v.w;
    }

    float acc_o[4][4] = {};
    float m_i = -INFINITY, l_i = 0.f;

    const int nt = (SEQ_ + TK - 1) / TK;
    for (int kt = 0; kt < nt; ++kt) {
        const int k0 = kt * TK;
#pragma unroll
        for (int rr = 0; rr < TK; rr += 16) {
            const int j = rr + r0;
            const int t = k0 + j;
            float4 kv = make_float4(0.f, 0.f, 0.f, 0.f);
            if (t < SEQ_) kv = *(const float4*)(Kg + (size_t)t * DH_ + dj);
            KVs[dj + 0][j] = kv.x; KVs[dj + 1][j] = kv.y;
            KVs[dj + 2][j] = kv.z; KVs[dj + 3][j] = kv.w;
        }
        __syncthreads();

        float acc[4][4] = {};
#pragma unroll
        for (int d = 0; d < DH_; ++d) {
            const float4 a = *(const float4*)&Qt[d][ty4];
            const float4 b = *(const float4*)&KVs[d][tx4];
            acc[0][0] += a.x * b.x; acc[0][1] += a.x * b.y; acc[0][2] += a.x * b.z; acc[0][3] += a.x * b.w;
            acc[1][0] += a.y * b.x; acc[1][1] += a.y * b.y; acc[1][2] += a.y * b.z; acc[1][3] += a.y * b.w;
            acc[2][0] += a.z * b.x; acc[2][1] += a.z * b.y; acc[2][2] += a.z * b.z; acc[2][3] += a.z * b.w;
            acc[3][0] += a.w * b.x; acc[3][1] += a.w * b.y; acc[3][2] += a.w * b.z; acc[3][3] += a.w * b.w;
        }
#pragma unroll
        for (int i = 0; i < 4; ++i) {
            float tmax = -INFINITY;
#pragma unroll
            for (int j = 0; j < 4; ++j) {
                float sv = acc[i][j] * 0.125f;
                if (k0 + tx4 + j >= SEQ_) sv = -INFINITY;
                Pt[tx4 + j][ty4 + i] = sv;
                tmax = fmaxf(tmax, sv);
            }
            pmax[tid & 15][ty4 + i] = tmax;
        }
        __syncthreads();

        float4 vreg[4];
#pragma unroll
        for (int rr = 0; rr < 4; ++rr) {
            const int j = rr * 16 + r0;
            const int t = k0 + j;
            vreg[rr] = make_float4(0.f, 0.f, 0.f, 0.f);
            if (t < SEQ_) vreg[rr] = *(const float4*)(Vg + (size_t)t * DH_ + dj);
        }
        if (tid < TQ) {
            float mt = pmax[0][tid];
#pragma unroll
            for (int g = 1; g < 16; ++g) mt = fmaxf(mt, pmax[g][tid]);
            const float mnew = fmaxf(m_i, mt);
            arow[tid] = expf(m_i - mnew);
            mrow[tid] = mnew;
            m_i = mnew;
        }
        __syncthreads();

#pragma unroll
        for (int rr = 0; rr < 4; ++rr) {
            const int j = rr * 16 + r0;
            *(float4*)&KVs[j][dj] = vreg[rr];
        }
        {
            const int r = tid & 63;
            const int g = tid >> 6;
            const float mr = mrow[r];
            float ps = 0.f;
#pragma unroll
            for (int jj = 0; jj < 16; ++jj) {
                const int j = g * 16 + jj;
                const float p = expf(Pt[j][r] - mr);
                Pt[j][r] = p;
                ps += p;
            }
            psum[g][r] = ps;
        }
        __syncthreads();

        if (tid < TQ)
            l_i = l_i * arow[tid] + psum[0][tid] + psum[1][tid] + psum[2][tid] + psum[3][tid];

#pragma unroll
        for (int i = 0; i < 4; ++i) {
            const float a = arow[ty4 + i];
            acc_o[i][0] *= a; acc_o[i][1] *= a; acc_o[i][2] *= a; acc_o[i][3] *= a;
        }
#pragma unroll
        for (int j = 0; j < TK; ++j) {
            const float4 p = *(const float4*)&Pt[j][ty4];
            const float4 v = *(const float4*)&KVs[j][tx4];
            acc_o[0][0] += p.x * v.x; acc_o[0][1] += p.x * v.y; acc_o[0][2] += p.x * v.z; acc_o[0][3] += p.x * v.w;
            acc_o[1][0] += p.y * v.x; acc_o[1][1] += p.y * v.y; acc_o[1][2] += p.y * v.z; acc_o[1][3] += p.y * v.w;
            acc_o[2][0] += p.z * v.x; acc_o[2][1] += p.z * v.y; acc_o[2][2] += p.z * v.z; acc_o[2][3] += p.z * v.w;
            acc_o[3][0] += p.w * v.x; acc_o[3][1] += p.w * v.y; acc_o[3][2] += p.w * v.z; acc_o[3][3] += p.w * v.w;
        }
        __syncthreads();
    }

    if (tid < TQ) arow[tid] = 1.f / l_i;
    __syncthreads();

    const int h = bh % NH_;
    const int b = bh / NH_;
#pragma unroll
    for (int i = 0; i < 4; ++i) {
        const int t = q0 + ty4 + i;
        if (t >= SEQ_) continue;
        const float inv = arow[ty4 + i];
        float* zp = z + ((size_t)b * SEQ_ + t) * D_ + h * DH_ + tx4;
        float4 o = *(const float4*)zp;
        o.x += acc_o[i][0] * inv;
        o.y += acc_o[i][1] * inv;
        o.z += acc_o[i][2] * inv;
        o.w += acc_o[i][3] * inv;
        *(float4*)zp = o;
    }
}

// ---------------------------------------------------------------------------
__global__ __launch_bounds__(256) void assemble_kernel(
    const float* __restrict__ P1, const float* __restrict__ P2,
    const float* __restrict__ cls, const float* __restrict__ pos,
    const float* __restrict__ st, float* __restrict__ z)
{
    const int i = blockIdx.x * 256 + threadIdx.x;
    const int d  = i % D_;
    const int bt = i / D_;
    const int t  = bt % SEQ_;
    const int b  = bt / SEQ_;
    float v = pos[t * D_ + d];
    v += (t < NST_) ? st[t * D_ + d]
                    : P2[((size_t)b * NSP_ + (t - NST_)) * D_ + d];
    v += (t == 0) ? cls[d]
                  : P1[((size_t)b * NPATCH_ + (t - 1)) * D_ + d];
    z[i] = v;
}

// ---------------------------------------------------------------------------
__global__ __launch_bounds__(256) void pool_kernel(
    const float* __restrict__ z, float* __restrict__ y)
{
    const int i = blockIdx.x * 256 + threadIdx.x;
    const int b = i / D_, d = i % D_;
    const float* p = z + (size_t)b * SEQ_ * D_ + d;
    float s = 0.f;
    for (int t = 0; t < SEQ_; ++t) s += p[(size_t)t * D_];
    y[i] = s * (1.f / SEQ_);
}

// ---------------------------------------------------------------------------
__global__ __launch_bounds__(256) void head_kernel(
    const float* __restrict__ y,
    const float* __restrict__ hn_s, const float* __restrict__ hn_b,
    const float* __restrict__ h1w, const float* __restrict__ h1b,
    const float* __restrict__ h2w, const float* __restrict__ h2b,
    const float* __restrict__ h3w, const float* __restrict__ h3b,
    float* __restrict__ out)
{
    const int b = blockIdx.x;
    const int tid = threadIdx.x;
    __shared__ float xn[D_];
    __shared__ float a1[256];
    __shared__ float a2[64];
    __shared__ float redS[4], redQ[4];

    const float* yr = y + (size_t)b * D_;
    const float v0 = yr[tid], v1 = yr[tid + 256], v2 = yr[tid + 512];
    float s = v0 + v1 + v2;
    float q = v0 * v0 + v1 * v1 + v2 * v2;
#pragma unroll
    for (int off = 32; off > 0; off >>= 1) {
        s += __shfl_down(s, off, 64);
        q += __shfl_down(q, off, 64);
    }
    if ((tid & 63) == 0) { redS[tid >> 6] = s; redQ[tid >> 6] = q; }
    __syncthreads();
    const float S = redS[0] + redS[1] + redS[2] + redS[3];
    const float Q = redQ[0] + redQ[1] + redQ[2] + redQ[3];
    const float mean = S * (1.f / D_);
    const float var  = Q * (1.f / D_) - mean * mean;
    const float inv  = rsqrtf(var + EPS_);
    xn[tid]       = (v0 - mean) * inv * hn_s[tid]       + hn_b[tid];
    xn[tid + 256] = (v1 - mean) * inv * hn_s[tid + 256] + hn_b[tid + 256];
    xn[tid + 512] = (v2 - mean) * inv * hn_s[tid + 512] + hn_b[tid + 512];
    __syncthreads();

    float s1 = h1b[tid];
    for (int k = 0; k < D_; ++k) s1 += xn[k] * h1w[k * 256 + tid];
    a1[tid] = s1;
    __syncthreads();

    if (tid < 64) {
        float s2 = h2b[tid];
        for (int k = 0; k < 256; ++k) s2 += a1[k] * h2w[k * 64 + tid];
        a2[tid] = s2;
    }
    __syncthreads();

    if (tid < 64) {
        float s3 = a2[tid] * h3w[tid];
#pragma unroll
        for (int off = 32; off > 0; off >>= 1)
            s3 += __shfl_down(s3, off, 64);
        if (tid == 0) out[b] = s3 + h3b[0];
    }
}

// ---------------------------------------------------------------------------
extern "C" void kernel_launch(void* const* d_in, const int* in_sizes, int n_in,
                              void* d_out, int out_size, void* d_ws, size_t ws_size,
                              hipStream_t stream)
{
    const float* input1    = (const float*)d_in[0];
    const float* input2    = (const float*)d_in[1];
    const float* proj_w    = (const float*)d_in[2];
    const float* proj_b    = (const float*)d_in[3];
    const float* cls_token = (const float*)d_in[4];
    const float* pos_emb   = (const float*)d_in[5];
    const float* strain    = (const float*)d_in[6];
    const float* ln1_s     = (const float*)d_in[7];
    const float* ln1_b     = (const float*)d_in[8];
    const float* wqkv      = (const float*)d_in[9];
    const float* ln2_s     = (const float*)d_in[10];
    const float* ln2_b     = (const float*)d_in[11];
    const float* fc1_w     = (const float*)d_in[12];
    const float* fc1_b     = (const float*)d_in[13];
    const float* fc2_w     = (const float*)d_in[14];
    const float* fc2_b     = (const float*)d_in[15];
    const float* hn_s      = (const float*)d_in[16];
    const float* hn_b      = (const float*)d_in[17];
    const float* h1_w      = (const float*)d_in[18];
    const float* h1_b      = (const float*)d_in[19];
    const float* h2_w      = (const float*)d_in[20];
    const float* h2_b      = (const float*)d_in[21];
    const float* h3_w      = (const float*)d_in[22];
    const float* h3_b      = (const float*)d_in[23];
    float* out = (float*)d_out;
    (void)in_sizes; (void)n_in; (void)out_size; (void)ws_size;

    // workspace layout (bytes):
    //   z      fp32 [TOK,768]                 25,214,976
    //   lnbh/l bf16 [TOK,768] x2              25,214,976
    //   big    max(QKV fp32 75.6MB, ffb hi/lo bf16 100.9MB)  100,859,904
    //   wbh/l  bf16 [3072,768]-max x2          9,437,184
    //   pooled fp32 [16,768]                      49,152
    // total ~160.8 MB
    char* W = (char*)d_ws;
    float*   z    = (float*)W;
    ushortT* lnbh = (ushortT*)(W + 25214976);
    ushortT* lnbl = lnbh + (size_t)TOK_ * D_;
    char*    big  = W + 25214976 + 2 * 12607488;
    float*   qkvp = (float*)big;
    ushortT* ffbh = (ushortT*)big;
    ushortT* ffbl = ffbh + (size_t)TOK_ * FF_;
    char*    wb   = big + 100859904;
    ushortT* wbh  = (ushortT*)wb;
    ushortT* wbl  = wbh + (size_t)FF_ * D_;
    float*   pooled = (float*)(wb + 2 * 9437184 / 2 + 0);  // after wbh+wbl
    pooled = (float*)(wb + 2 * (size_t)FF_ * D_ * 2);
    float*   P1 = (float*)big;
    float*   P2 = P1 + (size_t)B_ * NPATCH_ * D_;

    // 1) patch projections (fp32)
    gemm_f32<<<dim3(D_ / BN, (B_ * NPATCH_) / BM), 256, 0, stream>>>(
        input1, proj_w, proj_b, P1, B_ * NPATCH_, D_, 256);
    gemm_f32<<<dim3(D_ / BN, (B_ * NSP_) / BM), 256, 0, stream>>>(
        input2, proj_w, proj_b, P2, B_ * NSP_, D_, 256);

    // 2) assemble embeddings
    assemble_kernel<<<(TOK_ * D_) / 256, 256, 0, stream>>>(
        P1, P2, cls_token, pos_emb, strain, z);

    // 3) transformer layers
    const int mt = (TOK_ + GBM - 1) / GBM;     // 65
    const int qtiles = (SEQ_ + TQ - 1) / TQ;   // 9
    for (int l = 0; l < L_; ++l) {
        ln_bf_kernel<<<TOK_, 256, 0, stream>>>(z, ln1_s + l * D_, ln1_b + l * D_, lnbh, lnbl);
        wconv_kernel<<<dim3((3 * D_) / 64, D_ / 64), 256, 0, stream>>>(
            wqkv + (size_t)l * D_ * 3 * D_, wbh, wbl, 3 * D_, D_);
        mfma_gemm<<<dim3((3 * D_) / GBN, mt), 256, 0, stream>>>(
            lnbh, lnbl, wbh, wbl, nullptr, qkvp, nullptr, nullptr,
            TOK_, 3 * D_, D_, 1);
        attn_kernel<<<dim3(qtiles, B_ * NH_), 256, 0, stream>>>(qkvp, z);
        ln_bf_kernel<<<TOK_, 256, 0, stream>>>(z, ln2_s + l * D_, ln2_b + l * D_, lnbh, lnbl);
        wconv_kernel<<<dim3(FF_ / 64, D_ / 64), 256, 0, stream>>>(
            fc1_w + (size_t)l * D_ * FF_, wbh, wbl, FF_, D_);
        mfma_gemm<<<dim3(FF_ / GBN, mt), 256, 0, stream>>>(
            lnbh, lnbl, wbh, wbl, fc1_b + (size_t)l * FF_, nullptr, ffbh, ffbl,
            TOK_, FF_, D_, 2);
        wconv_kernel<<<dim3(D_ / 64, FF_ / 64), 256, 0, stream>>>(
            fc2_w + (size_t)l * FF_ * D_, wbh, wbl, D_, FF_);
        mfma_gemm<<<dim3(D_ / GBN, mt), 256, 0, stream>>>(
            ffbh, ffbl, wbh, wbl, fc2_b + (size_t)l * D_, z, nullptr, nullptr,
            TOK_, D_, FF_, 3);
    }

    // 4) head
    pool_kernel<<<(B_ * D_) / 256, 256, 0, stream>>>(z, pooled);
    head_kernel<<<B_, 256, 0, stream>>>(pooled, hn_s, hn_b,
        h1_w, h1_b, h2_w, h2_b, h3_w, h3_b, out);
}

// Round 4
// 8199.859 us; speedup vs baseline: 12.5674x; 1.2606x over previous
//
#include <hip/hip_runtime.h>
#include <math.h>

#define B_      16
#define SEQ_    513
#define D_      768
#define NH_     12
#define DH_     64
#define L_      12
#define FF_     3072
#define NPATCH_ 512
#define NSP_    128
#define NST_    385            // NPATCH - NSP + 1
#define TOK_    (B_ * SEQ_)    // 8208
#define EPS_    1e-5f
#define SEQP    576            // SEQ_ padded to 9*64
#define PLANE   ((size_t)(B_ * NH_) * SEQP * DH_)   // 7,077,888 halves/plane

typedef unsigned short ushortT;
typedef unsigned int   uintT;
typedef __attribute__((ext_vector_type(8))) short short8;
typedef __attribute__((ext_vector_type(4))) float floatx4;

__device__ __forceinline__ ushortT f2bf(float x) {
    uintT u = __float_as_uint(x);
    u += 0x7FFF + ((u >> 16) & 1);           // round-to-nearest-even
    return (ushortT)(u >> 16);
}
__device__ __forceinline__ float bf2f(ushortT h) {
    return __uint_as_float(((uintT)h) << 16);
}
// swizzled offset in a [r][64]-half LDS tile: 8-half group index XORed with
// (r&7) so quarter-wave fragment reads hit distinct 16B windows (no 128B-
// stride bank conflicts); 16B alignment preserved.
__device__ __forceinline__ int sw_off(int r, int k) {
    return r * 64 + ((((k >> 3) ^ (r & 7)) << 3) | (k & 7));
}

// ---------------------------------------------------------------------------
// fp32 tiled GEMM (patch embedding only). BM=BN=64, BK=16.
// ---------------------------------------------------------------------------
#define BM 64
#define BN 64
#define BK 16

__global__ __launch_bounds__(256) void gemm_f32(
    const float* __restrict__ A, const float* __restrict__ Bm,
    const float* __restrict__ bias, float* __restrict__ C,
    int M, int N, int K)
{
    __shared__ float As[BK][BM];
    __shared__ float Bs[BK][BN];
    const int tid  = threadIdx.x;
    const int row0 = blockIdx.y * BM;
    const int col0 = blockIdx.x * BN;
    const int ty4  = (tid >> 4) * 4;
    const int tx4  = (tid & 15) * 4;

    const int la   = tid * 4;
    const int arow = la >> 4;
    const int ak   = la & 15;
    const int brow = la >> 6;
    const int bcol = la & 63;

    float acc[4][4] = {};

    for (int k0 = 0; k0 < K; k0 += BK) {
        float4 av;
        if (row0 + arow < M)
            av = *(const float4*)(A + (size_t)(row0 + arow) * K + k0 + ak);
        else
            av = make_float4(0.f, 0.f, 0.f, 0.f);
        As[ak + 0][arow] = av.x;
        As[ak + 1][arow] = av.y;
        As[ak + 2][arow] = av.z;
        As[ak + 3][arow] = av.w;

        float4 bv = *(const float4*)(Bm + (size_t)(k0 + brow) * N + col0 + bcol);
        *(float4*)&Bs[brow][bcol] = bv;

        __syncthreads();
#pragma unroll
        for (int k = 0; k < BK; ++k) {
            const float4 a = *(const float4*)&As[k][ty4];
            const float4 b = *(const float4*)&Bs[k][tx4];
            acc[0][0] += a.x * b.x; acc[0][1] += a.x * b.y; acc[0][2] += a.x * b.z; acc[0][3] += a.x * b.w;
            acc[1][0] += a.y * b.x; acc[1][1] += a.y * b.y; acc[1][2] += a.y * b.z; acc[1][3] += a.y * b.w;
            acc[2][0] += a.z * b.x; acc[2][1] += a.z * b.y; acc[2][2] += a.z * b.z; acc[2][3] += a.z * b.w;
            acc[3][0] += a.w * b.x; acc[3][1] += a.w * b.y; acc[3][2] += a.w * b.z; acc[3][3] += a.w * b.w;
        }
        __syncthreads();
    }

#pragma unroll
    for (int i = 0; i < 4; ++i) {
        const int r = row0 + ty4 + i;
        if (r >= M) continue;
        float* crow = C + (size_t)r * N + col0 + tx4;
#pragma unroll
        for (int j = 0; j < 4; ++j)
            crow[j] = acc[i][j] + bias[col0 + tx4 + j];
    }
}

// ---------------------------------------------------------------------------
// Weight convert+transpose: W[K][N] fp32 -> Wt_hi[N][K], Wt_lo[N][K] bf16
// ---------------------------------------------------------------------------
__global__ __launch_bounds__(256) void wconv_kernel(
    const float* __restrict__ W, ushortT* __restrict__ Wh,
    ushortT* __restrict__ Wl, int N, int K)
{
    __shared__ float T[64][65];
    const int tid = threadIdx.x;
    const int n0 = blockIdx.x * 64;
    const int k0 = blockIdx.y * 64;
#pragma unroll
    for (int i = 0; i < 4; ++i) {
        const int idx = tid + 256 * i;
        const int kr = idx >> 4;
        const int nc = (idx & 15) * 4;
        float4 w = *(const float4*)(W + (size_t)(k0 + kr) * N + n0 + nc);
        T[kr][nc + 0] = w.x; T[kr][nc + 1] = w.y;
        T[kr][nc + 2] = w.z; T[kr][nc + 3] = w.w;
    }
    __syncthreads();
#pragma unroll
    for (int i = 0; i < 4; ++i) {
        const int idx = tid + 256 * i;
        const int nr = idx >> 4;
        const int kc = (idx & 15) * 4;
        uintT h01 = 0, h23 = 0, l01 = 0, l23 = 0;
#pragma unroll
        for (int j = 0; j < 4; ++j) {
            const float x = T[kc + j][nr];
            const ushortT h = f2bf(x);
            const ushortT l = f2bf(x - bf2f(h));
            if (j < 2) { h01 |= ((uintT)h) << (16 * j); l01 |= ((uintT)l) << (16 * j); }
            else       { h23 |= ((uintT)h) << (16 * (j - 2)); l23 |= ((uintT)l) << (16 * (j - 2)); }
        }
        const size_t off = (size_t)(n0 + nr) * K + k0 + kc;
        *(uint2*)(Wh + off) = make_uint2(h01, h23);
        *(uint2*)(Wl + off) = make_uint2(l01, l23);
    }
}

// ---------------------------------------------------------------------------
// bf16x3 MFMA GEMM. 128x128 tile, BK=32, 4 waves.
// mode 1: scatter bf16 hi/lo into 6 Q/K/V planes (Ch = plane base)
// mode 2: bias+GELU -> bf16 hi/lo planes Ch/Cl [M][N]
// mode 3: bias, Cf[M][N] += v
// ---------------------------------------------------------------------------
#define GBM 128
#define GBN 128
#define GBK 32

__global__ __launch_bounds__(256) void mfma_gemm(
    const ushortT* __restrict__ Ah, const ushortT* __restrict__ Al,
    const ushortT* __restrict__ Bh, const ushortT* __restrict__ Bl,
    const float* __restrict__ bias, float* __restrict__ Cf,
    ushortT* __restrict__ Ch, ushortT* __restrict__ Cl,
    int M, int N, int K, int mode)
{
    __shared__ __align__(16) ushortT Ahs[GBM * GBK];
    __shared__ __align__(16) ushortT Als[GBM * GBK];
    __shared__ __align__(16) ushortT Bhs[GBN * GBK];
    __shared__ __align__(16) ushortT Bls[GBN * GBK];

    const int tid  = threadIdx.x;
    const int row0 = blockIdx.y * GBM;
    const int col0 = blockIdx.x * GBN;
    const int lane = tid & 63;
    const int wv   = tid >> 6;
    const int wr   = wv >> 1;
    const int wc   = wv & 1;
    const int ln15 = lane & 15;
    const int lq   = lane >> 4;

    floatx4 acc[4][4];
#pragma unroll
    for (int i = 0; i < 4; ++i)
#pragma unroll
        for (int j = 0; j < 4; ++j)
            acc[i][j] = (floatx4){0.f, 0.f, 0.f, 0.f};

    for (int k0 = 0; k0 < K; k0 += GBK) {
#pragma unroll
        for (int cc = 0; cc < 2; ++cc) {
            const int c  = tid + 256 * cc;
            const int r  = c >> 2;
            const int ks = (c & 3) * 8;
            const uint4 z4 = make_uint4(0u, 0u, 0u, 0u);
            uint4 vh = z4, vl = z4;
            if (row0 + r < M) {
                const size_t go = (size_t)(row0 + r) * K + k0 + ks;
                vh = *(const uint4*)(Ah + go);
                vl = *(const uint4*)(Al + go);
            }
            *(uint4*)&Ahs[c * 8] = vh;
            *(uint4*)&Als[c * 8] = vl;
            const size_t bo = (size_t)(col0 + r) * K + k0 + ks;
            *(uint4*)&Bhs[c * 8] = *(const uint4*)(Bh + bo);
            *(uint4*)&Bls[c * 8] = *(const uint4*)(Bl + bo);
        }
        __syncthreads();

        short8 afh[4], afl[4], bfh[4], bfl[4];
#pragma unroll
        for (int i = 0; i < 4; ++i) {
            const int ao = (wr * 64 + i * 16 + ln15) * GBK + lq * 8;
            const int bo = (wc * 64 + i * 16 + ln15) * GBK + lq * 8;
            afh[i] = *(const short8*)&Ahs[ao];
            afl[i] = *(const short8*)&Als[ao];
            bfh[i] = *(const short8*)&Bhs[bo];
            bfl[i] = *(const short8*)&Bls[bo];
        }
#pragma unroll
        for (int mi = 0; mi < 4; ++mi)
#pragma unroll
            for (int ni = 0; ni < 4; ++ni) {
                acc[mi][ni] = __builtin_amdgcn_mfma_f32_16x16x32_bf16(afh[mi], bfh[ni], acc[mi][ni], 0, 0, 0);
                acc[mi][ni] = __builtin_amdgcn_mfma_f32_16x16x32_bf16(afh[mi], bfl[ni], acc[mi][ni], 0, 0, 0);
                acc[mi][ni] = __builtin_amdgcn_mfma_f32_16x16x32_bf16(afl[mi], bfh[ni], acc[mi][ni], 0, 0, 0);
            }
        __syncthreads();
    }

#pragma unroll
    for (int mi = 0; mi < 4; ++mi) {
#pragma unroll
        for (int ni = 0; ni < 4; ++ni) {
            const int cg = col0 + wc * 64 + ni * 16 + ln15;
#pragma unroll
            for (int reg = 0; reg < 4; ++reg) {
                const int rg = row0 + wr * 64 + mi * 16 + lq * 4 + reg;
                if (rg >= M) continue;
                float v = acc[mi][ni][reg];
                if (mode == 1) {
                    const int b   = rg / SEQ_;
                    const int t   = rg - b * SEQ_;
                    const int h   = cg / 192;
                    const int rem = cg - h * 192;
                    const int d   = rem / 3;
                    const int s   = rem - d * 3;
                    const size_t off = ((size_t)(b * NH_ + h) * SEQP + t) * DH_ + d;
                    const ushortT hh = f2bf(v);
                    Ch[(size_t)(2 * s) * PLANE + off]     = hh;
                    Ch[(size_t)(2 * s + 1) * PLANE + off] = f2bf(v - bf2f(hh));
                } else if (mode == 2) {
                    v += bias[cg];
                    v = v * 0.5f * (1.f + erff(v * 0.70710678118654752f));
                    const ushortT h16 = f2bf(v);
                    const size_t off = (size_t)rg * N + cg;
                    Ch[off] = h16;
                    Cl[off] = f2bf(v - bf2f(h16));
                } else {
                    v += bias[cg];
                    Cf[(size_t)rg * N + cg] += v;
                }
            }
        }
    }
}

// ---------------------------------------------------------------------------
// LayerNorm -> bf16 hi/lo planes
// ---------------------------------------------------------------------------
__global__ __launch_bounds__(256) void ln_bf_kernel(
    const float* __restrict__ x, const float* __restrict__ sc,
    const float* __restrict__ bi, ushortT* __restrict__ yh,
    ushortT* __restrict__ yl)
{
    const int row = blockIdx.x;
    const int tid = threadIdx.x;
    const float* xr = x + (size_t)row * D_;
    const float v0 = xr[tid], v1 = xr[tid + 256], v2 = xr[tid + 512];

    float s = v0 + v1 + v2;
    float q = v0 * v0 + v1 * v1 + v2 * v2;
#pragma unroll
    for (int off = 32; off > 0; off >>= 1) {
        s += __shfl_down(s, off, 64);
        q += __shfl_down(q, off, 64);
    }
    __shared__ float redS[4], redQ[4];
    if ((tid & 63) == 0) { redS[tid >> 6] = s; redQ[tid >> 6] = q; }
    __syncthreads();
    const float S = redS[0] + redS[1] + redS[2] + redS[3];
    const float Q = redQ[0] + redQ[1] + redQ[2] + redQ[3];
    const float mean = S * (1.f / D_);
    const float var  = Q * (1.f / D_) - mean * mean;
    const float inv  = rsqrtf(var + EPS_);

    const size_t base = (size_t)row * D_;
#pragma unroll
    for (int i = 0; i < 3; ++i) {
        const int d = tid + 256 * i;
        const float vv = (i == 0 ? v0 : (i == 1 ? v1 : v2));
        const float y  = (vv - mean) * inv * sc[d] + bi[d];
        const ushortT h = f2bf(y);
        yh[base + d] = h;
        yl[base + d] = f2bf(y - bf2f(h));
    }
}

// ---------------------------------------------------------------------------
// MFMA flash attention. Grid (9 qtiles, 192 bh), 256 threads (4 waves).
// Each wave owns 16 q-rows. Q/K/V bf16 hi/lo planes [bh][t pad 576][64].
// K/V tiles in swizzled LDS; per-quad online softmax; P round-trips through
// per-wave LDS (hi/lo) into A-layout; 3 MFMAs per logical product (bf16x3).
// ---------------------------------------------------------------------------
__global__ __launch_bounds__(256) void attn_mfma(
    const ushortT* __restrict__ qkvb, float* __restrict__ z)
{
    __shared__ __align__(16) ushortT Ksh[64 * 64];
    __shared__ __align__(16) ushortT Ksl[64 * 64];
    __shared__ __align__(16) ushortT Vsh[64 * 64];
    __shared__ __align__(16) ushortT Vsl[64 * 64];
    __shared__ __align__(16) ushortT Psh[4][16 * 64];
    __shared__ __align__(16) ushortT Psl[4][16 * 64];

    const int tid  = threadIdx.x;
    const int lane = tid & 63;
    const int w    = tid >> 6;
    const int l15  = lane & 15;
    const int quad = lane >> 4;
    const int q0   = blockIdx.x * 64;
    const int bh   = blockIdx.y;

    const size_t bho = (size_t)bh * SEQP * DH_;
    const ushortT* Qh = qkvb + 0 * PLANE + bho;
    const ushortT* Ql = qkvb + 1 * PLANE + bho;
    const ushortT* Kh = qkvb + 2 * PLANE + bho;
    const ushortT* Kl = qkvb + 3 * PLANE + bho;
    const ushortT* Vh = qkvb + 4 * PLANE + bho;
    const ushortT* Vl = qkvb + 5 * PLANE + bho;

    // Q A-fragments: rows m = l15 -> t = q0 + w*16 + l15, k = quad*8 (+32*ks)
    short8 qfh[2], qfl[2];
    {
        const int tq = q0 + w * 16 + l15;
        if (tq < SEQ_) {
            const size_t qo = (size_t)tq * DH_ + quad * 8;
            qfh[0] = *(const short8*)(Qh + qo);
            qfh[1] = *(const short8*)(Qh + qo + 32);
            qfl[0] = *(const short8*)(Ql + qo);
            qfl[1] = *(const short8*)(Ql + qo + 32);
        } else {
            const short8 z8 = (short8){0,0,0,0,0,0,0,0};
            qfh[0] = qfh[1] = qfl[0] = qfl[1] = z8;
        }
    }

    floatx4 acc_o[4];
#pragma unroll
    for (int i = 0; i < 4; ++i) acc_o[i] = (floatx4){0.f, 0.f, 0.f, 0.f};
    float m_old[4] = {-INFINITY, -INFINITY, -INFINITY, -INFINITY};
    float l_i[4]   = {0.f, 0.f, 0.f, 0.f};

    // staging indices: row jr, two 8-half groups at dc, dc+8
    const int jr = tid >> 2;
    const int dc = (tid & 3) * 16;

    for (int kt = 0; kt < 9; ++kt) {
        const int k0 = kt * 64;
        // ---- stage K (swizzled [j][d]) and V (swizzled transposed [d][j]) ----
        {
            const int tk = k0 + jr;
            const uint4 z4 = make_uint4(0u, 0u, 0u, 0u);
            uint4 kh0 = z4, kh1 = z4, kl0 = z4, kl1 = z4;
            union { uint4 u4[2]; ushortT s[16]; } uvh, uvl;
            uvh.u4[0] = z4; uvh.u4[1] = z4; uvl.u4[0] = z4; uvl.u4[1] = z4;
            if (tk < SEQ_) {
                const size_t go = (size_t)tk * DH_ + dc;
                kh0 = *(const uint4*)(Kh + go);
                kh1 = *(const uint4*)(Kh + go + 8);
                kl0 = *(const uint4*)(Kl + go);
                kl1 = *(const uint4*)(Kl + go + 8);
                uvh.u4[0] = *(const uint4*)(Vh + go);
                uvh.u4[1] = *(const uint4*)(Vh + go + 8);
                uvl.u4[0] = *(const uint4*)(Vl + go);
                uvl.u4[1] = *(const uint4*)(Vl + go + 8);
            }
            *(uint4*)&Ksh[sw_off(jr, dc)]     = kh0;
            *(uint4*)&Ksh[sw_off(jr, dc + 8)] = kh1;
            *(uint4*)&Ksl[sw_off(jr, dc)]     = kl0;
            *(uint4*)&Ksl[sw_off(jr, dc + 8)] = kl1;
#pragma unroll
            for (int i = 0; i < 16; ++i) {
                const int d = dc + i;
                Vsh[sw_off(d, jr)] = uvh.s[i];
                Vsl[sw_off(d, jr)] = uvl.s[i];
            }
        }
        __syncthreads();

        // ---- S = QK^T (bf16x3) ----
        floatx4 s4[4];
#pragma unroll
        for (int i = 0; i < 4; ++i) s4[i] = (floatx4){0.f, 0.f, 0.f, 0.f};
#pragma unroll
        for (int ks = 0; ks < 2; ++ks) {
#pragma unroll
            for (int ni = 0; ni < 4; ++ni) {
                const int off = sw_off(ni * 16 + l15, ks * 32 + quad * 8);
                const short8 kfh = *(const short8*)&Ksh[off];
                const short8 kfl = *(const short8*)&Ksl[off];
                s4[ni] = __builtin_amdgcn_mfma_f32_16x16x32_bf16(qfh[ks], kfh, s4[ni], 0, 0, 0);
                s4[ni] = __builtin_amdgcn_mfma_f32_16x16x32_bf16(qfh[ks], kfl, s4[ni], 0, 0, 0);
                s4[ni] = __builtin_amdgcn_mfma_f32_16x16x32_bf16(qfl[ks], kfh, s4[ni], 0, 0, 0);
            }
        }

        // ---- online softmax (rows = quad*4+reg, per-quad shuffle reduce) ----
        float sval[4][4];
        float tm[4] = {-INFINITY, -INFINITY, -INFINITY, -INFINITY};
#pragma unroll
        for (int ni = 0; ni < 4; ++ni) {
            const bool ok = (k0 + ni * 16 + l15) < SEQ_;
#pragma unroll
            for (int r = 0; r < 4; ++r) {
                float sv = ok ? s4[ni][r] * 0.125f : -INFINITY;
                sval[ni][r] = sv;
                tm[r] = fmaxf(tm[r], sv);
            }
        }
#pragma unroll
        for (int m = 1; m <= 8; m <<= 1)
#pragma unroll
            for (int r = 0; r < 4; ++r)
                tm[r] = fmaxf(tm[r], __shfl_xor(tm[r], m, 64));

        float alpha[4];
#pragma unroll
        for (int r = 0; r < 4; ++r) {
            const float mn = fmaxf(m_old[r], tm[r]);
            alpha[r] = __expf(m_old[r] - mn);
            m_old[r] = mn;
        }

        float rs[4] = {0.f, 0.f, 0.f, 0.f};
#pragma unroll
        for (int ni = 0; ni < 4; ++ni) {
#pragma unroll
            for (int r = 0; r < 4; ++r) {
                const float p = __expf(sval[ni][r] - m_old[r]);
                rs[r] += p;
                const int row = quad * 4 + r;
                const int col = ni * 16 + l15;
                const int off = sw_off(row, col);
                const ushortT ph = f2bf(p);
                Psh[w][off] = ph;
                Psl[w][off] = f2bf(p - bf2f(ph));
            }
        }
#pragma unroll
        for (int m = 1; m <= 8; m <<= 1)
#pragma unroll
            for (int r = 0; r < 4; ++r)
                rs[r] += __shfl_xor(rs[r], m, 64);
#pragma unroll
        for (int r = 0; r < 4; ++r)
            l_i[r] = l_i[r] * alpha[r] + rs[r];
#pragma unroll
        for (int ni = 0; ni < 4; ++ni)
#pragma unroll
            for (int r = 0; r < 4; ++r)
                acc_o[ni][r] *= alpha[r];
        __syncthreads();

        // ---- O += P V (bf16x3) ----
#pragma unroll
        for (int ks = 0; ks < 2; ++ks) {
            const int poff = sw_off(l15, ks * 32 + quad * 8);
            const short8 pfh = *(const short8*)&Psh[w][poff];
            const short8 pfl = *(const short8*)&Psl[w][poff];
#pragma unroll
            for (int ni = 0; ni < 4; ++ni) {
                const int voff = sw_off(ni * 16 + l15, ks * 32 + quad * 8);
                const short8 vfh = *(const short8*)&Vsh[voff];
                const short8 vfl = *(const short8*)&Vsl[voff];
                acc_o[ni] = __builtin_amdgcn_mfma_f32_16x16x32_bf16(pfh, vfh, acc_o[ni], 0, 0, 0);
                acc_o[ni] = __builtin_amdgcn_mfma_f32_16x16x32_bf16(pfh, vfl, acc_o[ni], 0, 0, 0);
                acc_o[ni] = __builtin_amdgcn_mfma_f32_16x16x32_bf16(pfl, vfh, acc_o[ni], 0, 0, 0);
            }
        }
        __syncthreads();
    }

    // ---- write O/l into residual z ----
    const int h = bh % NH_;
    const int b = bh / NH_;
#pragma unroll
    for (int r = 0; r < 4; ++r) {
        const int t = q0 + w * 16 + quad * 4 + r;
        if (t >= SEQ_) continue;
        const float inv = 1.f / l_i[r];
        float* zp = z + ((size_t)(b * SEQ_ + t)) * D_ + h * DH_;
#pragma unroll
        for (int ni = 0; ni < 4; ++ni) {
            const int d = ni * 16 + l15;
            zp[d] += acc_o[ni][r] * inv;
        }
    }
}

// ---------------------------------------------------------------------------
__global__ __launch_bounds__(256) void assemble_kernel(
    const float* __restrict__ P1, const float* __restrict__ P2,
    const float* __restrict__ cls, const float* __restrict__ pos,
    const float* __restrict__ st, float* __restrict__ z)
{
    const int i = blockIdx.x * 256 + threadIdx.x;
    const int d  = i % D_;
    const int bt = i / D_;
    const int t  = bt % SEQ_;
    const int b  = bt / SEQ_;
    float v = pos[t * D_ + d];
    v += (t < NST_) ? st[t * D_ + d]
                    : P2[((size_t)b * NSP_ + (t - NST_)) * D_ + d];
    v += (t == 0) ? cls[d]
                  : P1[((size_t)b * NPATCH_ + (t - 1)) * D_ + d];
    z[i] = v;
}

// ---------------------------------------------------------------------------
__global__ __launch_bounds__(256) void pool_kernel(
    const float* __restrict__ z, float* __restrict__ y)
{
    const int i = blockIdx.x * 256 + threadIdx.x;
    const int b = i / D_, d = i % D_;
    const float* p = z + (size_t)b * SEQ_ * D_ + d;
    float s = 0.f;
    for (int t = 0; t < SEQ_; ++t) s += p[(size_t)t * D_];
    y[i] = s * (1.f / SEQ_);
}

// ---------------------------------------------------------------------------
__global__ __launch_bounds__(256) void head_kernel(
    const float* __restrict__ y,
    const float* __restrict__ hn_s, const float* __restrict__ hn_b,
    const float* __restrict__ h1w, const float* __restrict__ h1b,
    const float* __restrict__ h2w, const float* __restrict__ h2b,
    const float* __restrict__ h3w, const float* __restrict__ h3b,
    float* __restrict__ out)
{
    const int b = blockIdx.x;
    const int tid = threadIdx.x;
    __shared__ float xn[D_];
    __shared__ float a1[256];
    __shared__ float a2[64];
    __shared__ float redS[4], redQ[4];

    const float* yr = y + (size_t)b * D_;
    const float v0 = yr[tid], v1 = yr[tid + 256], v2 = yr[tid + 512];
    float s = v0 + v1 + v2;
    float q = v0 * v0 + v1 * v1 + v2 * v2;
#pragma unroll
    for (int off = 32; off > 0; off >>= 1) {
        s += __shfl_down(s, off, 64);
        q += __shfl_down(q, off, 64);
    }
    if ((tid & 63) == 0) { redS[tid >> 6] = s; redQ[tid >> 6] = q; }
    __syncthreads();
    const float S = redS[0] + redS[1] + redS[2] + redS[3];
    const float Q = redQ[0] + redQ[1] + redQ[2] + redQ[3];
    const float mean = S * (1.f / D_);
    const float var  = Q * (1.f / D_) - mean * mean;
    const float inv  = rsqrtf(var + EPS_);
    xn[tid]       = (v0 - mean) * inv * hn_s[tid]       + hn_b[tid];
    xn[tid + 256] = (v1 - mean) * inv * hn_s[tid + 256] + hn_b[tid + 256];
    xn[tid + 512] = (v2 - mean) * inv * hn_s[tid + 512] + hn_b[tid + 512];
    __syncthreads();

    float s1 = h1b[tid];
    for (int k = 0; k < D_; ++k) s1 += xn[k] * h1w[k * 256 + tid];
    a1[tid] = s1;
    __syncthreads();

    if (tid < 64) {
        float s2 = h2b[tid];
        for (int k = 0; k < 256; ++k) s2 += a1[k] * h2w[k * 64 + tid];
        a2[tid] = s2;
    }
    __syncthreads();

    if (tid < 64) {
        float s3 = a2[tid] * h3w[tid];
#pragma unroll
        for (int off = 32; off > 0; off >>= 1)
            s3 += __shfl_down(s3, off, 64);
        if (tid == 0) out[b] = s3 + h3b[0];
    }
}

// ---------------------------------------------------------------------------
extern "C" void kernel_launch(void* const* d_in, const int* in_sizes, int n_in,
                              void* d_out, int out_size, void* d_ws, size_t ws_size,
                              hipStream_t stream)
{
    const float* input1    = (const float*)d_in[0];
    const float* input2    = (const float*)d_in[1];
    const float* proj_w    = (const float*)d_in[2];
    const float* proj_b    = (const float*)d_in[3];
    const float* cls_token = (const float*)d_in[4];
    const float* pos_emb   = (const float*)d_in[5];
    const float* strain    = (const float*)d_in[6];
    const float* ln1_s     = (const float*)d_in[7];
    const float* ln1_b     = (const float*)d_in[8];
    const float* wqkv      = (const float*)d_in[9];
    const float* ln2_s     = (const float*)d_in[10];
    const float* ln2_b     = (const float*)d_in[11];
    const float* fc1_w     = (const float*)d_in[12];
    const float* fc1_b     = (const float*)d_in[13];
    const float* fc2_w     = (const float*)d_in[14];
    const float* fc2_b     = (const float*)d_in[15];
    const float* hn_s      = (const float*)d_in[16];
    const float* hn_b      = (const float*)d_in[17];
    const float* h1_w      = (const float*)d_in[18];
    const float* h1_b      = (const float*)d_in[19];
    const float* h2_w      = (const float*)d_in[20];
    const float* h2_b      = (const float*)d_in[21];
    const float* h3_w      = (const float*)d_in[22];
    const float* h3_b      = (const float*)d_in[23];
    float* out = (float*)d_out;
    (void)in_sizes; (void)n_in; (void)out_size; (void)ws_size;

    // workspace layout (bytes):
    //   z      fp32 [TOK,768]                      25,214,976
    //   lnbh/l bf16 [TOK,768] x2                   25,214,976
    //   big    max(QKV bf16 planes 84.9MB, ffb hi/lo 100.9MB, P1/P2 75.6MB)
    //                                             100,859,904
    //   wbh/l  bf16 [3072,768]-max x2               9,437,184
    //   pooled fp32 [16,768]                           49,152
    char* W = (char*)d_ws;
    float*   z    = (float*)W;
    ushortT* lnbh = (ushortT*)(W + 25214976);
    ushortT* lnbl = lnbh + (size_t)TOK_ * D_;
    char*    big  = W + 25214976 + 2 * 12607488;
    ushortT* qkvb = (ushortT*)big;                  // 6 planes * PLANE halves
    ushortT* ffbh = (ushortT*)big;
    ushortT* ffbl = ffbh + (size_t)TOK_ * FF_;
    char*    wb   = big + 100859904;
    ushortT* wbh  = (ushortT*)wb;
    ushortT* wbl  = wbh + (size_t)FF_ * D_;
    float*   pooled = (float*)(wb + 2 * (size_t)FF_ * D_ * 2);
    float*   P1 = (float*)big;
    float*   P2 = P1 + (size_t)B_ * NPATCH_ * D_;

    // 1) patch projections (fp32)
    gemm_f32<<<dim3(D_ / BN, (B_ * NPATCH_) / BM), 256, 0, stream>>>(
        input1, proj_w, proj_b, P1, B_ * NPATCH_, D_, 256);
    gemm_f32<<<dim3(D_ / BN, (B_ * NSP_) / BM), 256, 0, stream>>>(
        input2, proj_w, proj_b, P2, B_ * NSP_, D_, 256);

    // 2) assemble embeddings
    assemble_kernel<<<(TOK_ * D_) / 256, 256, 0, stream>>>(
        P1, P2, cls_token, pos_emb, strain, z);

    // 3) transformer layers
    const int mt = (TOK_ + GBM - 1) / GBM;     // 65
    for (int l = 0; l < L_; ++l) {
        ln_bf_kernel<<<TOK_, 256, 0, stream>>>(z, ln1_s + l * D_, ln1_b + l * D_, lnbh, lnbl);
        wconv_kernel<<<dim3((3 * D_) / 64, D_ / 64), 256, 0, stream>>>(
            wqkv + (size_t)l * D_ * 3 * D_, wbh, wbl, 3 * D_, D_);
        mfma_gemm<<<dim3((3 * D_) / GBN, mt), 256, 0, stream>>>(
            lnbh, lnbl, wbh, wbl, nullptr, nullptr, qkvb, nullptr,
            TOK_, 3 * D_, D_, 1);
        attn_mfma<<<dim3(SEQP / 64, B_ * NH_), 256, 0, stream>>>(qkvb, z);
        ln_bf_kernel<<<TOK_, 256, 0, stream>>>(z, ln2_s + l * D_, ln2_b + l * D_, lnbh, lnbl);
        wconv_kernel<<<dim3(FF_ / 64, D_ / 64), 256, 0, stream>>>(
            fc1_w + (size_t)l * D_ * FF_, wbh, wbl, FF_, D_);
        mfma_gemm<<<dim3(FF_ / GBN, mt), 256, 0, stream>>>(
            lnbh, lnbl, wbh, wbl, fc1_b + (size_t)l * FF_, nullptr, ffbh, ffbl,
            TOK_, FF_, D_, 2);
        wconv_kernel<<<dim3(D_ / 64, FF_ / 64), 256, 0, stream>>>(
            fc2_w + (size_t)l * FF_ * D_, wbh, wbl, D_, FF_);
        mfma_gemm<<<dim3(D_ / GBN, mt), 256, 0, stream>>>(
            ffbh, ffbl, wbh, wbl, fc2_b + (size_t)l * D_, z, nullptr, nullptr,
            TOK_, D_, FF_, 3);
    }

    // 4) head
    pool_kernel<<<(B_ * D_) / 256, 256, 0, stream>>>(z, pooled);
    head_kernel<<<B_, 256, 0, stream>>>(pooled, hn_s, hn_b,
        h1_w, h1_b, h2_w, h2_b, h3_w, h3_b, out);
}